// Round 16
// baseline (404.516 us; speedup 1.0000x reference)
//
#include <hip/hip_runtime.h>
#include <math.h>

// RAMEN layer. Round 16: k_gemm_p switched to 2-buffer/32KB LDS (5 blocks/CU,
// TLP over pipeline depth — m97-style). Isolated A/B: silu/fuse2_64/p64 kernels
// unchanged from R15 (392.7us).
// T=2048, X_D=2048, M_D=256, M_N=64, CHUNK=64, FF_D=2816.

typedef short bhalf8 __attribute__((ext_vector_type(8)));
typedef float f32x4 __attribute__((ext_vector_type(4)));

#define CC_LD 7168
#define COL_V   0
#define COL_B1  2048
#define COL_B2  4096
#define COL_QB  6144
#define COL_VM  6400
#define COL_QM  6656
#define COL_FG  6912

#define AS1 __attribute__((address_space(1)))
#define AS3 __attribute__((address_space(3)))

__device__ __forceinline__ float sigmoidf_(float x){ return 1.0f/(1.0f+expf(-x)); }

__device__ __forceinline__ unsigned short f2b(float f){
  unsigned u = __float_as_uint(f);
  unsigned r = (u + 0x7fffu + ((u>>16)&1u)) >> 16;
  return (unsigned short)r;
}
__device__ __forceinline__ float b2f(unsigned short h){
  return __uint_as_float(((unsigned)h)<<16);
}

// ---------------- mega prep: weight converts + mem_k transpose + trig + norm ----
__global__ __launch_bounds__(256) void k_prep(
    const float* __restrict__ av, const float* __restrict__ ar, const float* __restrict__ mr,
    const float* __restrict__ aq, const float* __restrict__ mv, const float* __restrict__ mq,
    const float* __restrict__ mf, const float* __restrict__ ao, const float* __restrict__ mo,
    const float* __restrict__ f1, const float* __restrict__ f2, const float* __restrict__ fo,
    const float* __restrict__ ak, const float* __restrict__ mk,
    const float* __restrict__ xsrc, const float* __restrict__ g1,
    unsigned short* __restrict__ WCAT, unsigned short* __restrict__ AOB,
    unsigned short* __restrict__ MOB, unsigned short* __restrict__ FFW,
    unsigned short* __restrict__ FFOB, unsigned short* __restrict__ AKB,
    unsigned short* __restrict__ MKTB, float2* __restrict__ TR,
    unsigned short* __restrict__ XNb){
  int bid = blockIdx.x, tid = threadIdx.x;
  if (bid < 35520){
    int i = bid*256 + tid;  // float4 index
    const float* s; unsigned short* d; int off;
    if (i < 3571712){
      d = WCAT + (size_t)i*4;
      if      (i < 1048576){ s = av; off = i; }
      else if (i < 2097152){ s = ar; off = i-1048576; }
      else if (i < 3145728){ s = mr; off = i-2097152; }
      else if (i < 3276800){ s = aq; off = i-3145728; }
      else if (i < 3407872){ s = mv; off = i-3276800; }
      else if (i < 3538944){ s = mq; off = i-3407872; }
      else                 { s = mf; off = i-3538944; }
    }
    else if (i < 4620288){ off = i-3571712; s = ao; d = AOB  + (size_t)off*4; }
    else if (i < 4751360){ off = i-4620288; s = mo; d = MOB  + (size_t)off*4; }
    else if (i < 6193152){ off = i-4751360; s = f1;
      int row = off >> 9, c4 = off & 511;
      d = FFW + ((size_t)row*2)*2048 + c4*4; }
    else if (i < 7634944){ off = i-6193152; s = f2;
      int row = off >> 9, c4 = off & 511;
      d = FFW + ((size_t)row*2 + 1)*2048 + c4*4; }
    else if (i < 9076736){ off = i-7634944; s = fo; d = FFOB + (size_t)off*4; }
    else if (i < 9093120){ off = i-9076736; s = ak; d = AKB  + (size_t)off*4; }
    else return;
    float4 v = ((const float4*)s)[off];
    ushort4 o;
    o.x = f2b(v.x); o.y = f2b(v.y); o.z = f2b(v.z); o.w = f2b(v.w);
    *(ushort4*)d = o;
  } else if (bid < 35776){
    int i = bid - 35520, j = tid;
    MKTB[(size_t)j*256 + i] = f2b(mk[(size_t)i*256 + j]);
  } else if (bid < 35840){
    int idx = (bid - 35776)*256 + tid;   // 16384
    int pos = idx >> 7, j = idx & 127;
    float inv = powf(10000.f, -(float)j/128.f);
    float a = (float)pos * inv;
    TR[idx] = make_float2(cosf(a), sinf(a));
  } else {
    int row = bid - 35840;
    const float* xr = xsrc + (size_t)row*2048;
    float ss = 0.f;
    for (int j = tid; j < 2048; j += 256){ float v = xr[j]; ss += v*v; }
    __shared__ float red[256];
    red[tid] = ss; __syncthreads();
    for (int s = 128; s > 0; s >>= 1){ if (tid < s) red[tid] += red[tid+s]; __syncthreads(); }
    float scale = g1[0] / (sqrtf(red[0]) + 1e-8f);
    unsigned short* orow = XNb + (size_t)row*2048;
    for (int j4 = tid; j4 < 512; j4 += 256){
      float4 v = *(const float4*)(xr + j4*4);
      ushort4 o;
      o.x = f2b(v.x*scale); o.y = f2b(v.y*scale); o.z = f2b(v.z*scale); o.w = f2b(v.w*scale);
      ((ushort4*)orow)[j4] = o;
    }
  }
}

// ---------------- scale norm -> bf16 (for XS2) ----------------------------------
__global__ __launch_bounds__(256) void k_scalenorm_b(const float* __restrict__ x,
    const float* __restrict__ g, unsigned short* __restrict__ ob){
  int row = blockIdx.x, tid = threadIdx.x;
  const float* xr = x + (size_t)row*2048;
  float ss = 0.f;
  for (int j = tid; j < 2048; j += 256){ float v = xr[j]; ss += v*v; }
  __shared__ float red[256];
  red[tid] = ss; __syncthreads();
  for (int s = 128; s > 0; s >>= 1){ if (tid < s) red[tid] += red[tid+s]; __syncthreads(); }
  float scale = g[0] / (sqrtf(red[0]) + 1e-8f);
  unsigned short* orow = ob + (size_t)row*2048;
  for (int j4 = tid; j4 < 512; j4 += 256){
    float4 v = *(const float4*)(xr + j4*4);
    ushort4 o;
    o.x = f2b(v.x*scale); o.y = f2b(v.y*scale); o.z = f2b(v.z*scale); o.w = f2b(v.w*scale);
    ((ushort4*)orow)[j4] = o;
  }
}

// ---------------- pipelined bf16 MFMA GEMM (128x128), 2-buffer/32KB -------------
// 128x128 tile, BK=32, 4 waves (64x64 each), 2 LDS buffers -> 5 blocks/CU.
// stage(t+1) while compute(t); vmcnt(0)+barrier per K-step (drain hidden by TLP).
// blockIdx.z==1 -> use A2/B2/C2. epi: 0 C f32(+add); 2 *sigmoid(gate); 3 Cb bf16.
__global__ __launch_bounds__(256) void k_gemm_p(
    const unsigned short* __restrict__ A, int lda,
    const unsigned short* __restrict__ B,
    float* __restrict__ C, unsigned short* __restrict__ Cb,
    int N, int K, int ldc, int epi,
    const float* __restrict__ add,
    const unsigned short* __restrict__ gate, int gate_ld,
    const unsigned short* A2, const unsigned short* B2, float* C2){
  __shared__ unsigned short LDSu[16384];     // 2 x 16KB = 32 KB
  int tid = threadIdx.x;
  int w = tid >> 6, l = tid & 63;
  int bi = blockIdx.y, bj = blockIdx.x;
  const unsigned short* Ap = A; const unsigned short* Bp = B; float* Cp = C;
  if (blockIdx.z){ Ap = A2; Bp = B2; Cp = C2; }
  int m0 = bi*128, n0 = bj*128;
  int wr = w >> 1, wc = w & 1;

  f32x4 acc[4][4];
#pragma unroll
  for (int i=0;i<4;++i)
#pragma unroll
    for (int j=0;j<4;++j){ f32x4 z = {0.f,0.f,0.f,0.f}; acc[i][j] = z; }

  const int r0 = tid >> 2;
  const int gsrc8 = (((tid&3) ^ ((tid>>3)&3)) * 8);

  auto stage = [&](int bs, int kt){
    unsigned short* db = LDSu + bs*8192;
    const unsigned short* ap0 = Ap + (size_t)(m0 + r0)*lda      + kt*32 + gsrc8;
    const unsigned short* ap1 = Ap + (size_t)(m0 + 64 + r0)*lda + kt*32 + gsrc8;
    const unsigned short* bp0 = Bp + (size_t)(n0 + r0)*K        + kt*32 + gsrc8;
    const unsigned short* bp1 = Bp + (size_t)(n0 + 64 + r0)*K   + kt*32 + gsrc8;
    __builtin_amdgcn_global_load_lds((const AS1 void*)ap0, (AS3 void*)(db + tid*8),        16, 0, 0);
    __builtin_amdgcn_global_load_lds((const AS1 void*)ap1, (AS3 void*)(db + 2048 + tid*8), 16, 0, 0);
    __builtin_amdgcn_global_load_lds((const AS1 void*)bp0, (AS3 void*)(db + 4096 + tid*8), 16, 0, 0);
    __builtin_amdgcn_global_load_lds((const AS1 void*)bp1, (AS3 void*)(db + 6144 + tid*8), 16, 0, 0);
  };

  const int nt = K >> 5;
  stage(0, 0);
  asm volatile("s_waitcnt vmcnt(0)" ::: "memory");
  __builtin_amdgcn_s_barrier();

  const int lr = l & 15;
  const int gsw = (((l>>4) ^ ((l>>1)&3)) * 8);
  const int aoff = (wr*64 + lr)*32 + gsw;
  const int boff = 4096 + (wc*64 + lr)*32 + gsw;

  int cur = 0;
  for (int t = 0; t < nt; ++t){
    if (t + 1 < nt) stage(cur ^ 1, t+1);
    const unsigned short* Tb = LDSu + cur*8192;
    bhalf8 af[4], bfr[4];
#pragma unroll
    for (int m=0;m<4;++m) af[m]  = *(const bhalf8*)(Tb + aoff + m*512);
#pragma unroll
    for (int n=0;n<4;++n) bfr[n] = *(const bhalf8*)(Tb + boff + n*512);
    __builtin_amdgcn_s_setprio(1);
#pragma unroll
    for (int m=0;m<4;++m)
#pragma unroll
      for (int n=0;n<4;++n)
        acc[m][n] = __builtin_amdgcn_mfma_f32_16x16x32_bf16(af[m], bfr[n], acc[m][n], 0, 0, 0);
    __builtin_amdgcn_s_setprio(0);
    if (t + 1 < nt){
      asm volatile("s_waitcnt vmcnt(0)" ::: "memory");
      __builtin_amdgcn_s_barrier();
      cur ^= 1;
    }
  }

#pragma unroll
  for (int m=0;m<4;++m){
    int rowb = m0 + wr*64 + m*16 + ((l>>4)<<2);
#pragma unroll
    for (int r=0;r<4;++r){
      int row = rowb + r;
      size_t rbase = (size_t)row*ldc;
      size_t gbase = (size_t)row*gate_ld;
#pragma unroll
      for (int n=0;n<4;++n){
        int col = n0 + wc*64 + n*16 + (l&15);
        float v = acc[m][n][r];
        if (add) v += add[rbase + col];
        if (epi == 2) v *= sigmoidf_(b2f(gate[gbase + col]));
        if (epi == 3) Cb[rbase + col] = f2b(v);
        else          Cp[rbase + col] = v;
      }
    }
  }
}

// ---------------- BN=64 pipelined GEMM: C = A @ B^T + add (f32 out) -------------
// BM=128, BN=64, BK=32, 4 waves (64x32 each), 3x12KB LDS, counted vmcnt(3).
__global__ __launch_bounds__(256) void k_gemm_p64(
    const unsigned short* __restrict__ A, int lda,
    const unsigned short* __restrict__ B,
    float* __restrict__ C, int K, int ldc,
    const float* __restrict__ add){
  __shared__ unsigned short LDSu[18432];     // 36 KB
  int tid = threadIdx.x;
  int w = tid >> 6, l = tid & 63;
  int bi = blockIdx.y, bj = blockIdx.x;
  int m0 = bi*128, n0 = bj*64;
  int wr = w >> 1, wc = w & 1;

  f32x4 acc[4][2];
#pragma unroll
  for (int i=0;i<4;++i)
#pragma unroll
    for (int j=0;j<2;++j){ f32x4 z = {0.f,0.f,0.f,0.f}; acc[i][j] = z; }

  const int r0 = tid >> 2;
  const int gsrc8 = (((tid&3) ^ ((tid>>3)&3)) * 8);

  auto stage = [&](int bs, int kt){
    unsigned short* db = LDSu + bs*6144;
    const unsigned short* ap0 = A + (size_t)(m0 + r0)*lda      + kt*32 + gsrc8;
    const unsigned short* ap1 = A + (size_t)(m0 + 64 + r0)*lda + kt*32 + gsrc8;
    const unsigned short* bp0 = B + (size_t)(n0 + r0)*K        + kt*32 + gsrc8;
    __builtin_amdgcn_global_load_lds((const AS1 void*)ap0, (AS3 void*)(db + tid*8),        16, 0, 0);
    __builtin_amdgcn_global_load_lds((const AS1 void*)ap1, (AS3 void*)(db + 2048 + tid*8), 16, 0, 0);
    __builtin_amdgcn_global_load_lds((const AS1 void*)bp0, (AS3 void*)(db + 4096 + tid*8), 16, 0, 0);
  };

  const int nt = K >> 5;
  stage(0, 0);
  stage(1, 1);
  asm volatile("s_waitcnt vmcnt(3)" ::: "memory");
  __builtin_amdgcn_s_barrier();

  const int lr = l & 15;
  const int gsw = (((l>>4) ^ ((l>>1)&3)) * 8);
  const int aoff = (wr*64 + lr)*32 + gsw;
  const int boff = 4096 + (wc*32 + lr)*32 + gsw;

  int cur = 0;
  for (int t = 0; t < nt; ++t){
    if (t + 2 < nt) stage((t+2)%3, t+2);
    const unsigned short* Tb = LDSu + cur*6144;
    bhalf8 af[4], bfr[2];
#pragma unroll
    for (int m=0;m<4;++m) af[m]  = *(const bhalf8*)(Tb + aoff + m*512);
#pragma unroll
    for (int n=0;n<2;++n) bfr[n] = *(const bhalf8*)(Tb + boff + n*512);
    __builtin_amdgcn_s_setprio(1);
#pragma unroll
    for (int m=0;m<4;++m)
#pragma unroll
      for (int n=0;n<2;++n)
        acc[m][n] = __builtin_amdgcn_mfma_f32_16x16x32_bf16(af[m], bfr[n], acc[m][n], 0, 0, 0);
    __builtin_amdgcn_s_setprio(0);
    if (t + 1 < nt){
      if (t + 2 < nt){ asm volatile("s_waitcnt vmcnt(3)" ::: "memory"); }
      else           { asm volatile("s_waitcnt vmcnt(0)" ::: "memory"); }
      __builtin_amdgcn_s_barrier();
      cur = (cur == 2) ? 0 : cur + 1;
    }
  }

#pragma unroll
  for (int m=0;m<4;++m){
    int rowb = m0 + wr*64 + m*16 + ((l>>4)<<2);
#pragma unroll
    for (int r=0;r<4;++r){
      int row = rowb + r;
      size_t rbase = (size_t)row*ldc;
#pragma unroll
      for (int n=0;n<2;++n){
        int col = n0 + wc*32 + n*16 + (l&15);
        C[rbase + col] = acc[m][n][r] + add[rbase + col];
      }
    }
  }
}

// ---------------- BN=64 fused AO+MO GEMM -> XS2 ---------------------------------
__global__ __launch_bounds__(256) void k_gemm_fuse2_64(
    const unsigned short* __restrict__ A,  const unsigned short* __restrict__ B,
    const unsigned short* __restrict__ A2, const unsigned short* __restrict__ B2,
    const unsigned short* __restrict__ gate1, const unsigned short* __restrict__ gate2,
    const float* __restrict__ xs, float* __restrict__ XS2){
  __shared__ unsigned short LDSu[18432];
  int tid = threadIdx.x;
  int w = tid >> 6, l = tid & 63;
  int bi = blockIdx.y, bj = blockIdx.x;
  int m0 = bi*128, n0 = bj*64;
  int wr = w >> 1, wc = w & 1;

  f32x4 acc[4][2], acc2[4][2];
#pragma unroll
  for (int i=0;i<4;++i)
#pragma unroll
    for (int j=0;j<2;++j){ f32x4 z = {0.f,0.f,0.f,0.f}; acc[i][j] = z; acc2[i][j] = z; }

  const int r0 = tid >> 2;
  const int gsrc8 = (((tid&3) ^ ((tid>>3)&3)) * 8);

  auto stage = [&](int bs, int kt, const unsigned short* Ap, int lda,
                   const unsigned short* Bp, int ldb){
    unsigned short* db = LDSu + bs*6144;
    const unsigned short* ap0 = Ap + (size_t)(m0 + r0)*lda      + kt*32 + gsrc8;
    const unsigned short* ap1 = Ap + (size_t)(m0 + 64 + r0)*lda + kt*32 + gsrc8;
    const unsigned short* bp0 = Bp + (size_t)(n0 + r0)*ldb      + kt*32 + gsrc8;
    __builtin_amdgcn_global_load_lds((const AS1 void*)ap0, (AS3 void*)(db + tid*8),        16, 0, 0);
    __builtin_amdgcn_global_load_lds((const AS1 void*)ap1, (AS3 void*)(db + 2048 + tid*8), 16, 0, 0);
    __builtin_amdgcn_global_load_lds((const AS1 void*)bp0, (AS3 void*)(db + 4096 + tid*8), 16, 0, 0);
  };

  const int lr = l & 15;
  const int gsw = (((l>>4) ^ ((l>>1)&3)) * 8);
  const int aoff = (wr*64 + lr)*32 + gsw;
  const int boff = 4096 + (wc*32 + lr)*32 + gsw;

  {
    const int nt = 64;
    stage(0, 0, A, 2048, B, 2048);
    stage(1, 1, A, 2048, B, 2048);
    asm volatile("s_waitcnt vmcnt(3)" ::: "memory");
    __builtin_amdgcn_s_barrier();
    int cur = 0;
    for (int t = 0; t < nt; ++t){
      if (t + 2 < nt) stage((t+2)%3, t+2, A, 2048, B, 2048);
      const unsigned short* Tb = LDSu + cur*6144;
      bhalf8 af[4], bfr[2];
#pragma unroll
      for (int m=0;m<4;++m) af[m]  = *(const bhalf8*)(Tb + aoff + m*512);
#pragma unroll
      for (int n=0;n<2;++n) bfr[n] = *(const bhalf8*)(Tb + boff + n*512);
      __builtin_amdgcn_s_setprio(1);
#pragma unroll
      for (int m=0;m<4;++m)
#pragma unroll
        for (int n=0;n<2;++n)
          acc[m][n] = __builtin_amdgcn_mfma_f32_16x16x32_bf16(af[m], bfr[n], acc[m][n], 0, 0, 0);
      __builtin_amdgcn_s_setprio(0);
      if (t + 1 < nt){
        if (t + 2 < nt){ asm volatile("s_waitcnt vmcnt(3)" ::: "memory"); }
        else           { asm volatile("s_waitcnt vmcnt(0)" ::: "memory"); }
        __builtin_amdgcn_s_barrier();
        cur = (cur == 2) ? 0 : cur + 1;
      }
    }
  }
  __syncthreads();

  {
    const int nt = 8;
    stage(0, 0, A2, 256, B2, 256);
    stage(1, 1, A2, 256, B2, 256);
    asm volatile("s_waitcnt vmcnt(3)" ::: "memory");
    __builtin_amdgcn_s_barrier();
    int cur = 0;
    for (int t = 0; t < nt; ++t){
      if (t + 2 < nt) stage((t+2)%3, t+2, A2, 256, B2, 256);
      const unsigned short* Tb = LDSu + cur*6144;
      bhalf8 af[4], bfr[2];
#pragma unroll
      for (int m=0;m<4;++m) af[m]  = *(const bhalf8*)(Tb + aoff + m*512);
#pragma unroll
      for (int n=0;n<2;++n) bfr[n] = *(const bhalf8*)(Tb + boff + n*512);
      __builtin_amdgcn_s_setprio(1);
#pragma unroll
      for (int m=0;m<4;++m)
#pragma unroll
        for (int n=0;n<2;++n)
          acc2[m][n] = __builtin_amdgcn_mfma_f32_16x16x32_bf16(af[m], bfr[n], acc2[m][n], 0, 0, 0);
      __builtin_amdgcn_s_setprio(0);
      if (t + 1 < nt){
        if (t + 2 < nt){ asm volatile("s_waitcnt vmcnt(3)" ::: "memory"); }
        else           { asm volatile("s_waitcnt vmcnt(0)" ::: "memory"); }
        __builtin_amdgcn_s_barrier();
        cur = (cur == 2) ? 0 : cur + 1;
      }
    }
  }

#pragma unroll
  for (int m=0;m<4;++m){
    int rowb = m0 + wr*64 + m*16 + ((l>>4)<<2);
#pragma unroll
    for (int r=0;r<4;++r){
      int row = rowb + r;
      size_t gb = (size_t)row*CC_LD;
      size_t rb = (size_t)row*2048;
#pragma unroll
      for (int n=0;n<2;++n){
        int col = n0 + wc*32 + n*16 + (l&15);
        float v = acc[m][n][r]*sigmoidf_(b2f(gate1[gb + col]))
                + acc2[m][n][r]*sigmoidf_(b2f(gate2[gb + col]))
                + xs[rb + col];
        XS2[rb + col] = v;
      }
    }
  }
}

// ---------------- SiLU-pair GEMM (FF-in) ----------------------------------------
__global__ __launch_bounds__(256) void k_gemm_silu(
    const unsigned short* __restrict__ A, int lda,
    const unsigned short* __restrict__ B,
    unsigned short* __restrict__ Cb, int K, int out_ld){
  __shared__ unsigned short LDSu[24576];
  int tid = threadIdx.x;
  int w = tid >> 6, l = tid & 63;
  int bi = blockIdx.y, bj = blockIdx.x;
  int m0 = bi*128, n0 = bj*128;
  int wr = w >> 1, wc = w & 1;

  f32x4 acc[4][4];
#pragma unroll
  for (int i=0;i<4;++i)
#pragma unroll
    for (int j=0;j<4;++j){ f32x4 z = {0.f,0.f,0.f,0.f}; acc[i][j] = z; }

  const int r0 = tid >> 2;
  const int gsrc8 = (((tid&3) ^ ((tid>>3)&3)) * 8);

  auto stage = [&](int bs, int kt){
    unsigned short* db = LDSu + bs*8192;
    const unsigned short* ap0 = A + (size_t)(m0 + r0)*lda      + kt*32 + gsrc8;
    const unsigned short* ap1 = A + (size_t)(m0 + 64 + r0)*lda + kt*32 + gsrc8;
    const unsigned short* bp0 = B + (size_t)(n0 + r0)*K        + kt*32 + gsrc8;
    const unsigned short* bp1 = B + (size_t)(n0 + 64 + r0)*K   + kt*32 + gsrc8;
    __builtin_amdgcn_global_load_lds((const AS1 void*)ap0, (AS3 void*)(db + tid*8),        16, 0, 0);
    __builtin_amdgcn_global_load_lds((const AS1 void*)ap1, (AS3 void*)(db + 2048 + tid*8), 16, 0, 0);
    __builtin_amdgcn_global_load_lds((const AS1 void*)bp0, (AS3 void*)(db + 4096 + tid*8), 16, 0, 0);
    __builtin_amdgcn_global_load_lds((const AS1 void*)bp1, (AS3 void*)(db + 6144 + tid*8), 16, 0, 0);
  };

  const int nt = K >> 5;
  stage(0, 0);
  stage(1, 1);
  asm volatile("s_waitcnt vmcnt(4)" ::: "memory");
  __builtin_amdgcn_s_barrier();

  const int lr = l & 15;
  const int gsw = (((l>>4) ^ ((l>>1)&3)) * 8);
  const int aoff = (wr*64 + lr)*32 + gsw;
  const int boff = 4096 + (wc*64 + lr)*32 + gsw;

  int cur = 0;
  for (int t = 0; t < nt; ++t){
    if (t + 2 < nt) stage((t+2)%3, t+2);
    const unsigned short* Tb = LDSu + cur*8192;
    bhalf8 af[4], bfr[4];
#pragma unroll
    for (int m=0;m<4;++m) af[m]  = *(const bhalf8*)(Tb + aoff + m*512);
#pragma unroll
    for (int n=0;n<4;++n) bfr[n] = *(const bhalf8*)(Tb + boff + n*512);
    __builtin_amdgcn_s_setprio(1);
#pragma unroll
    for (int m=0;m<4;++m)
#pragma unroll
      for (int n=0;n<4;++n)
        acc[m][n] = __builtin_amdgcn_mfma_f32_16x16x32_bf16(af[m], bfr[n], acc[m][n], 0, 0, 0);
    __builtin_amdgcn_s_setprio(0);
    if (t + 1 < nt){
      if (t + 2 < nt){ asm volatile("s_waitcnt vmcnt(4)" ::: "memory"); }
      else           { asm volatile("s_waitcnt vmcnt(0)" ::: "memory"); }
      __builtin_amdgcn_s_barrier();
      cur = (cur == 2) ? 0 : cur + 1;
    }
  }

#pragma unroll
  for (int m=0;m<4;++m){
    int rowb = m0 + wr*64 + m*16 + ((l>>4)<<2);
#pragma unroll
    for (int r=0;r<4;++r){
      int row = rowb + r;
      size_t gbase = (size_t)row*out_ld;
#pragma unroll
      for (int n=0;n<4;++n){
        int col = n0 + wc*64 + n*16 + (l&15);
        float v = acc[m][n][r];
        float o = __shfl_xor(v, 1);
        if ((l & 1) == 0)
          Cb[gbase + (col>>1)] = f2b(v*sigmoidf_(v)*o);
      }
    }
  }
}

// ---------------- fused attention scores+softmax (MFMA) -------------------------
__global__ __launch_bounds__(256) void k_attn_scores_mfma(
    const unsigned short* __restrict__ CCqb, const float* __restrict__ K0,
    const float2* __restrict__ TR, unsigned short* __restrict__ P){
  __shared__ unsigned short Ks[128*256];   // 64 KB
  int c = blockIdx.x, tid = threadIdx.x;
  for (int it = 0; it < 16; ++it){
    int id = tid + it*256;          // 0..4095
    int m = id >> 5;                // key row 0..127, rope pos = m
    int cs = (id & 31) * 8;         // f32 col start
    float v[8];
    if (c == 0 && m < 64){
#pragma unroll
      for (int u=0;u<8;++u) v[u] = 0.f;
    } else {
      int gr = (c-1)*64 + m;
      const float* kr = K0 + (size_t)gr*256 + cs;
      float4 x0 = *(const float4*)kr, x1 = *(const float4*)(kr+4);
      v[0]=x0.x; v[1]=x0.y; v[2]=x0.z; v[3]=x0.w;
      v[4]=x1.x; v[5]=x1.y; v[6]=x1.z; v[7]=x1.w;
#pragma unroll
      for (int p2=0;p2<4;++p2){
        float2 t = TR[m*128 + (cs>>1) + p2];
        float e = v[2*p2], o = v[2*p2+1];
        v[2*p2]   = e*t.x - o*t.y;
        v[2*p2+1] = o*t.x + e*t.y;
      }
    }
    unsigned short pk[8];
#pragma unroll
    for (int u=0;u<8;++u) pk[u] = f2b(v[u]);
    int byte = m*512 + ((cs*2) ^ ((m&7)<<4));
    *(bhalf8*)((char*)&Ks[0] + byte) = *(const bhalf8*)pk;
  }
  __syncthreads();

  int w = tid >> 6, l = tid & 63;
  int lr = l & 15, lkg = l >> 4;
  f32x4 acc[8];
#pragma unroll
  for (int n=0;n<8;++n){ f32x4 z = {0.f,0.f,0.f,0.f}; acc[n] = z; }

  int iq = w*16 + lr;
  const unsigned short* qbase = CCqb + (size_t)(c*64 + iq)*CC_LD;
  int pos = 64 + iq;

  for (int kt = 0; kt < 8; ++kt){
    int k0c = kt*32 + lkg*8;
    bhalf8 q8 = *(const bhalf8*)(qbase + k0c);
    float v[8];
#pragma unroll
    for (int u=0;u<8;++u) v[u] = b2f((unsigned short)(((short*)&q8)[u]));
#pragma unroll
    for (int p2=0;p2<4;++p2){
      float2 t = TR[pos*128 + (k0c>>1) + p2];
      float e = v[2*p2], o = v[2*p2+1];
      v[2*p2]   = e*t.x - o*t.y;
      v[2*p2+1] = o*t.x + e*t.y;
    }
    unsigned short pk[8];
#pragma unroll
    for (int u=0;u<8;++u) pk[u] = f2b(v[u]);
    bhalf8 af = *(const bhalf8*)pk;
#pragma unroll
    for (int n=0;n<8;++n){
      int m = n*16 + lr;
      int byte = m*512 + ((k0c*2) ^ ((m&7)<<4));
      bhalf8 bf = *(const bhalf8*)((const char*)&Ks[0] + byte);
      acc[n] = __builtin_amdgcn_mfma_f32_16x16x32_bf16(af, bf, acc[n], 0, 0, 0);
    }
  }

  int i0 = w*16 + lkg*4;
  float mx[4] = {-1e30f,-1e30f,-1e30f,-1e30f};
  float sm[4] = {0.f,0.f,0.f,0.f};
#pragma unroll
  for (int n=0;n<8;++n){
    int col = n*16 + lr;
#pragma unroll
    for (int r=0;r<4;++r){
      float vv = acc[n][r] * (1.f/16.f);
      if (col > i0 + r + 64) vv = -1e30f;
      acc[n][r] = vv;
      mx[r] = fmaxf(mx[r], vv);
    }
  }
#pragma unroll
  for (int s=1; s<16; s<<=1)
#pragma unroll
    for (int r=0;r<4;++r) mx[r] = fmaxf(mx[r], __shfl_xor(mx[r], s));
#pragma unroll
  for (int n=0;n<8;++n)
#pragma unroll
    for (int r=0;r<4;++r){
      float e = expf(acc[n][r] - mx[r]);
      acc[n][r] = e; sm[r] += e;
    }
#pragma unroll
  for (int s=1; s<16; s<<=1)
#pragma unroll
    for (int r=0;r<4;++r) sm[r] += __shfl_xor(sm[r], s);
  float rcp[4];
#pragma unroll
  for (int r=0;r<4;++r) rcp[r] = 1.f/sm[r];

  unsigned short* Pr = P + (size_t)c*8192;
#pragma unroll
  for (int n=0;n<8;++n){
    int col = n*16 + lr;
#pragma unroll
    for (int r=0;r<4;++r)
      Pr[(i0+r)*128 + col] = f2b(acc[n][r]*rcp[r]);
  }
}

// ---------------- MFMA PV: Y[c*64+i, ct*128+:] = P[c] @ V2[c] -------------------
__global__ __launch_bounds__(256) void k_attn_pv_mfma(
    const unsigned short* __restrict__ P, const unsigned short* __restrict__ Vb, int vld,
    unsigned short* __restrict__ Y){
  __shared__ unsigned short Vt[128*128];   // [col][k] swizzled, 32 KB
  int ct = blockIdx.x, c = blockIdx.y, tid = threadIdx.x;
  {
    int k = tid >> 1;               // V2 row 0..127
    int ch = (tid & 1) * 64;        // col half
    if (c == 0 && k < 64){
      for (int u=0; u<64; ++u){
        int col = ch + u;
        int byte = col*256 + ((k*2) ^ ((col&7)<<4));
        *(unsigned short*)((char*)&Vt[0] + byte) = 0;
      }
    } else {
      int gr = (c-1)*64 + k;
      const unsigned short* vr = Vb + (size_t)gr*vld + ct*128 + ch;
      for (int u8=0; u8<8; ++u8){
        bhalf8 x = *(const bhalf8*)(vr + u8*8);
#pragma unroll
        for (int u=0;u<8;++u){
          int col = ch + u8*8 + u;
          int byte = col*256 + ((k*2) ^ ((col&7)<<4));
          *(unsigned short*)((char*)&Vt[0] + byte) = (unsigned short)(((short*)&x)[u]);
        }
      }
    }
  }
  __syncthreads();
  int w = tid >> 6, l = tid & 63, lr = l & 15, lkg = l >> 4;
  f32x4 acc[8];
#pragma unroll
  for (int n=0;n<8;++n){ f32x4 z = {0.f,0.f,0.f,0.f}; acc[n] = z; }
  const unsigned short* Pr = P + (size_t)c*8192;
  for (int kt=0; kt<4; ++kt){
    int kb = kt*32 + lkg*8;
    bhalf8 af = *(const bhalf8*)(Pr + (w*16 + lr)*128 + kb);
#pragma unroll
    for (int n=0;n<8;++n){
      int col = n*16 + lr;
      int byte = col*256 + ((kb*2) ^ ((col&7)<<4));
      bhalf8 bf = *(const bhalf8*)((const char*)&Vt[0] + byte);
      acc[n] = __builtin_amdgcn_mfma_f32_16x16x32_bf16(af, bf, acc[n], 0, 0, 0);
    }
  }
  int row0 = c*64 + w*16 + lkg*4;
#pragma unroll
  for (int n=0;n<8;++n){
    int col = ct*128 + n*16 + lr;
#pragma unroll
    for (int r=0;r<4;++r)
      Y[(size_t)(row0+r)*2048 + col] = f2b(acc[n][r]);
  }
}

// ---------------- mem scan, chunk=16, 8 memories per block ----------------------
__global__ __launch_bounds__(256) void k_scan1(const unsigned short* __restrict__ CC,
    const float* __restrict__ beta_p, const float* __restrict__ decay_p,
    float* __restrict__ CP, float* __restrict__ CQ){
  int c = blockIdx.x, mg = blockIdx.y, d = threadIdx.x;
  __shared__ float Fs[128];
  if (threadIdx.x < 128){
    int s = threadIdx.x >> 3, j = threadIdx.x & 7;
    Fs[threadIdx.x] = sigmoidf_(b2f(CC[(size_t)(c*16+s)*CC_LD + COL_FG + mg*8 + j]));
  }
  __syncthreads();
  float beta[8], gamma[8], Pa[8], Qa[8];
#pragma unroll
  for (int j=0;j<8;++j){
    int m = mg*8+j;
    beta[j]  = sigmoidf_(beta_p[m*256+d]);
    gamma[j] = (d < 192) ? 1.f : sigmoidf_(decay_p[m*64 + (d-192)]);
    Pa[j] = 1.f; Qa[j] = 0.f;
  }
  for (int s = 0; s < 16; ++s){
    float vm = b2f(CC[(size_t)(c*16+s)*CC_LD + COL_VM + d]);
#pragma unroll
    for (int j=0;j<8;++j){
      float f = Fs[s*8+j];
      float w = (1.f - f*beta[j])*gamma[j];
      Pa[j] *= w;
      Qa[j] = w*Qa[j] + f*vm;
    }
  }
#pragma unroll
  for (int j=0;j<8;++j){
    size_t idx = ((size_t)c*64 + mg*8 + j)*256 + d;
    CP[idx] = Pa[j]; CQ[idx] = Qa[j];
  }
}

__global__ __launch_bounds__(256) void k_scan2(const float* __restrict__ CP,
    const float* __restrict__ CQ, float* __restrict__ SIN){
  int m = blockIdx.x, d = threadIdx.x;
  float S = 0.f;
  for (int c = 0; c < 128; ++c){
    size_t idx = ((size_t)c*64 + m)*256 + d;
    SIN[idx] = S;
    S = CP[idx]*S + CQ[idx];
  }
}

__global__ __launch_bounds__(256) void k_scan3(const unsigned short* __restrict__ CC,
    const float* __restrict__ beta_p, const float* __restrict__ decay_p,
    const float* __restrict__ SIN, unsigned short* __restrict__ MEMS){
  int c = blockIdx.x, mg = blockIdx.y, d = threadIdx.x;
  __shared__ float Fs[128];
  if (threadIdx.x < 128){
    int s = threadIdx.x >> 3, j = threadIdx.x & 7;
    Fs[threadIdx.x] = sigmoidf_(b2f(CC[(size_t)(c*16+s)*CC_LD + COL_FG + mg*8 + j]));
  }
  __syncthreads();
  float beta[8], gamma[8], S[8];
#pragma unroll
  for (int j=0;j<8;++j){
    int m = mg*8+j;
    beta[j]  = sigmoidf_(beta_p[m*256+d]);
    gamma[j] = (d < 192) ? 1.f : sigmoidf_(decay_p[m*64 + (d-192)]);
    S[j] = SIN[((size_t)c*64 + m)*256 + d];
  }
  for (int s = 0; s < 16; ++s){
    float vm = b2f(CC[(size_t)(c*16+s)*CC_LD + COL_VM + d]);
    size_t tb = (size_t)(c*16+s)*64;
#pragma unroll
    for (int j=0;j<8;++j){
      float f = Fs[s*8+j];
      float w = (1.f - f*beta[j])*gamma[j];
      S[j] = w*S[j] + f*vm;
      MEMS[(tb + mg*8 + j)*256 + d] = f2b(S[j]);
    }
  }
}

// ---------------- mem readout (wave-parallel softmax, vectorized pass 2) --------
__global__ __launch_bounds__(256) void k_memread(const unsigned short* __restrict__ MEMS,
    const float* __restrict__ QH, const unsigned short* __restrict__ QMs, int qm_ld,
    const float* __restrict__ L, unsigned short* __restrict__ YMb){
  int t = blockIdx.x, tid = threadIdx.x;
  int wave = tid >> 6, lane = tid & 63;
  __shared__ float anorm[64];
  __shared__ float red2[4][64][4];
  const unsigned short* Mt = MEMS + (size_t)t*16384;
  float4 qh4 = *(const float4*)(QH + (size_t)t*256 + lane*4);
  ushort4 qmu = *(const ushort4*)(QMs + (size_t)t*qm_ld + lane*4);
  float qm0 = b2f(qmu.x), qm1 = b2f(qmu.y), qm2 = b2f(qmu.z), qm3 = b2f(qmu.w);
  for (int mi = 0; mi < 16; ++mi){
    int m = wave*16 + mi;
    ushort4 su = *(const ushort4*)(Mt + m*256 + lane*4);
    float4 l4 = *(const float4*)(L + (size_t)m*256 + lane*4);
    float p = b2f(su.x)*qh4.x + b2f(su.y)*qh4.y + b2f(su.z)*qh4.z + b2f(su.w)*qh4.w
            + l4.x*qm0 + l4.y*qm1 + l4.z*qm2 + l4.w*qm3;
#pragma unroll
    for (int off = 32; off > 0; off >>= 1) p += __shfl_down(p, off);
    if (lane == 0) anorm[m] = p * (1.f/16.f);
  }
  __syncthreads();
  if (tid < 64){
    float v = anorm[tid];
    float mx = v;
#pragma unroll
    for (int off = 32; off > 0; off >>= 1) mx = fmaxf(mx, __shfl_xor(mx, off));
    float e = expf(v - mx);
    float s = e;
#pragma unroll
    for (int off = 32; off > 0; off >>= 1) s += __shfl_xor(s, off);
    anorm[tid] = e / s;
  }
  __syncthreads();
  int mq = tid >> 6, dq = tid & 63;
  float a0=0.f, a1=0.f, a2=0.f, a3=0.f;
#pragma unroll
  for (int mi = 0; mi < 16; ++mi){
    int m = mq*16 + mi;
    ushort4 su = *(const ushort4*)(Mt + m*256 + dq*4);
    float wgt = anorm[m];
    a0 += wgt*b2f(su.x); a1 += wgt*b2f(su.y);
    a2 += wgt*b2f(su.z); a3 += wgt*b2f(su.w);
  }
  red2[mq][dq][0]=a0; red2[mq][dq][1]=a1; red2[mq][dq][2]=a2; red2[mq][dq][3]=a3;
  __syncthreads();
  if (tid < 64){
    float r0=0.f, r1=0.f, r2=0.f, r3=0.f;
#pragma unroll
    for (int g=0; g<4; ++g){
      r0 += red2[g][tid][0]; r1 += red2[g][tid][1];
      r2 += red2[g][tid][2]; r3 += red2[g][tid][3];
    }
    ushort4 o;
    o.x = f2b(r0); o.y = f2b(r1); o.z = f2b(r2); o.w = f2b(r3);
    *(ushort4*)(YMb + (size_t)t*256 + tid*4) = o;
  }
}

// ---------------- launch ---------------------------------------------------------
extern "C" void kernel_launch(void* const* d_in, const int* in_sizes, int n_in,
                              void* d_out, int out_size, void* d_ws, size_t ws_size,
                              hipStream_t stream){
  const float* xs        = (const float*)d_in[0];
  const float* attn_q    = (const float*)d_in[1];
  const float* attn_k    = (const float*)d_in[2];
  const float* attn_v    = (const float*)d_in[3];
  const float* attn_o    = (const float*)d_in[4];
  const float* attn_r    = (const float*)d_in[5];
  const float* mem_f     = (const float*)d_in[6];
  const float* mem_q     = (const float*)d_in[7];
  const float* mem_k     = (const float*)d_in[8];
  const float* mem_v     = (const float*)d_in[9];
  const float* mem_o     = (const float*)d_in[10];
  const float* mem_r     = (const float*)d_in[11];
  const float* mem_beta  = (const float*)d_in[12];
  const float* mem_decay = (const float*)d_in[13];
  const float* mem_l     = (const float*)d_in[14];
  const float* ff1       = (const float*)d_in[15];
  const float* ff2       = (const float*)d_in[16];
  const float* ffo       = (const float*)d_in[17];
  const float* sn1       = (const float*)d_in[18];
  const float* sn2       = (const float*)d_in[19];
  float* out = (float*)d_out;
  float* W = (float*)d_ws;

  // ---- workspace layout (float offsets), ~246 MB ----
  unsigned short* XNb  = (unsigned short*)(W + 0);           // 2,097,152
  unsigned short* WCAT = (unsigned short*)(W + 2097152);     // 7,340,032 (7168x2048)
  unsigned short* CCb  = (unsigned short*)(W + 9437184);     // 7,340,032 (2048x7168)
  unsigned short* AOB  = (unsigned short*)(W + 16777216);    // 2,097,152
  unsigned short* MOB  = (unsigned short*)(W + 18874368);    // 262,144
  unsigned short* FFW  = (unsigned short*)(W + 19136512);    // 5,767,168 (interleaved ff1/ff2)
  unsigned short* FFOB = (unsigned short*)(W + 24903680);    // 2,883,584
  unsigned short* AKB  = (unsigned short*)(W + 27787264);    // 32,768
  unsigned short* MKTB = (unsigned short*)(W + 27820032);    // 32,768
  unsigned short* Ybb  = (unsigned short*)(W + 27852800);    // 2,097,152
  float*          XS2  = W + 34144256;                       // 4,194,304
  unsigned short* MEMSb= (unsigned short*)(W + 38338560);    // 16,777,216
  float*          CP   = W + 55115776;                       // 2,097,152 (128x64x256)
  float*          CQ   = W + 57212928;                       // 2,097,152
  float*          SIN  = W + 59310080;                       // 2,097,152
  float2*         TRIG = (float2*)(W + 61407232);            // 32,768 fl
  // aliases (sequential liveness):
  float*          K0   = W + 32768;                          // over XNb (dead after CC GEMM)
  unsigned short* P    = (unsigned short*)(W + 557056);      // over XNb
  float*          QH   = W + 688128;                         // over XNb
  unsigned short* YMb  = (unsigned short*)(W + 1212416);     // over XNb
  unsigned short* XN2b = MEMSb;                              // over MEMSb (dead after memread)
  unsigned short* H1b  = (unsigned short*)(W + 40435712);    // over MEMSb tail (2048x2816 bf16)

  dim3 blk(256);

  // ---- mega prep: converts + mem_k transpose + trig + scalenorm1 ----
  k_prep<<<dim3(37888), blk, 0, stream>>>(attn_v, attn_r, mem_r, attn_q, mem_v, mem_q,
      mem_f, attn_o, mem_o, ff1, ff2, ffo, attn_k, mem_k, xs, sn1,
      WCAT, AOB, MOB, FFW, FFOB, AKB, MKTB, TRIG, XNb);

  // ---- BIG concat GEMM (V + gates + QB + VM + QM + FG), bf16 out ----
  k_gemm_p<<<dim3(56, 16), blk, 0, stream>>>(XNb, 2048, WCAT, nullptr, CCb, CC_LD, 2048, CC_LD, 3,
      nullptr, nullptr, 0, nullptr, nullptr, nullptr);

  // ---- batched small GEMMs: z=0 -> K0 = QB @ attn_k^T ; z=1 -> QH = QM @ mem_k
  k_gemm_p<<<dim3(2, 16, 2), blk, 0, stream>>>(CCb + COL_QB, CC_LD, AKB, K0, nullptr, 256, 256, 256, 0,
      nullptr, nullptr, 0, CCb + COL_QM, MKTB, QH);

  // ---- attention scores + PV ----
  k_attn_scores_mfma<<<dim3(32), blk, 0, stream>>>(CCb + COL_QB, K0, TRIG, P);
  k_attn_pv_mfma<<<dim3(16, 32), blk, 0, stream>>>(P, CCb + COL_V, CC_LD, Ybb);

  // ---- memory branch (chunk=16 scan) ----
  k_scan1<<<dim3(128, 8), blk, 0, stream>>>(CCb, mem_beta, mem_decay, CP, CQ);
  k_scan2<<<dim3(64), blk, 0, stream>>>(CP, CQ, SIN);
  k_scan3<<<dim3(128, 8), blk, 0, stream>>>(CCb, mem_beta, mem_decay, SIN, MEMSb);
  k_memread<<<dim3(2048), blk, 0, stream>>>(MEMSb, QH, CCb + COL_QM, CC_LD, mem_l, YMb);

  // ---- fused AO+MO -> XS2 = attn_out + mem_out + xs (BN=64, 512 blocks) ----
  k_gemm_fuse2_64<<<dim3(32, 16), blk, 0, stream>>>(Ybb, AOB, YMb, MOB,
      CCb + COL_B1, CCb + COL_B2, xs, XS2);

  // ---- xn2 = scalenorm(XS2) -> bf16 ----
  k_scalenorm_b<<<dim3(2048), blk, 0, stream>>>(XS2, sn2, XN2b);

  // ---- FF: SiLU-fused GEMM -> H1b, then BN=64 out GEMM (512 blocks) ----
  k_gemm_silu<<<dim3(44, 16), blk, 0, stream>>>(XN2b, 2048, FFW, H1b, 2048, 2816);
  k_gemm_p64<<<dim3(32, 16), blk, 0, stream>>>(H1b, 2816, FFOB, out, 2816, 2048, XS2);
}

// Round 17
// 390.702 us; speedup vs baseline: 1.0354x; 1.0354x over previous
//
#include <hip/hip_runtime.h>
#include <math.h>

// RAMEN layer. Round 17: revert k_gemm_p to R15's 3-buffer/48KB counted-vmcnt
// pipeline (R16's 2-buffer TLP variant measured -12% on CC). Full R15 config
// (best measured 392.7us).
// T=2048, X_D=2048, M_D=256, M_N=64, CHUNK=64, FF_D=2816.

typedef short bhalf8 __attribute__((ext_vector_type(8)));
typedef float f32x4 __attribute__((ext_vector_type(4)));

#define CC_LD 7168
#define COL_V   0
#define COL_B1  2048
#define COL_B2  4096
#define COL_QB  6144
#define COL_VM  6400
#define COL_QM  6656
#define COL_FG  6912

#define AS1 __attribute__((address_space(1)))
#define AS3 __attribute__((address_space(3)))

__device__ __forceinline__ float sigmoidf_(float x){ return 1.0f/(1.0f+expf(-x)); }

__device__ __forceinline__ unsigned short f2b(float f){
  unsigned u = __float_as_uint(f);
  unsigned r = (u + 0x7fffu + ((u>>16)&1u)) >> 16;
  return (unsigned short)r;
}
__device__ __forceinline__ float b2f(unsigned short h){
  return __uint_as_float(((unsigned)h)<<16);
}

// ---------------- mega prep: weight converts + mem_k transpose + trig + norm ----
__global__ __launch_bounds__(256) void k_prep(
    const float* __restrict__ av, const float* __restrict__ ar, const float* __restrict__ mr,
    const float* __restrict__ aq, const float* __restrict__ mv, const float* __restrict__ mq,
    const float* __restrict__ mf, const float* __restrict__ ao, const float* __restrict__ mo,
    const float* __restrict__ f1, const float* __restrict__ f2, const float* __restrict__ fo,
    const float* __restrict__ ak, const float* __restrict__ mk,
    const float* __restrict__ xsrc, const float* __restrict__ g1,
    unsigned short* __restrict__ WCAT, unsigned short* __restrict__ AOB,
    unsigned short* __restrict__ MOB, unsigned short* __restrict__ FFW,
    unsigned short* __restrict__ FFOB, unsigned short* __restrict__ AKB,
    unsigned short* __restrict__ MKTB, float2* __restrict__ TR,
    unsigned short* __restrict__ XNb){
  int bid = blockIdx.x, tid = threadIdx.x;
  if (bid < 35520){
    int i = bid*256 + tid;  // float4 index
    const float* s; unsigned short* d; int off;
    if (i < 3571712){
      d = WCAT + (size_t)i*4;
      if      (i < 1048576){ s = av; off = i; }
      else if (i < 2097152){ s = ar; off = i-1048576; }
      else if (i < 3145728){ s = mr; off = i-2097152; }
      else if (i < 3276800){ s = aq; off = i-3145728; }
      else if (i < 3407872){ s = mv; off = i-3276800; }
      else if (i < 3538944){ s = mq; off = i-3407872; }
      else                 { s = mf; off = i-3538944; }
    }
    else if (i < 4620288){ off = i-3571712; s = ao; d = AOB  + (size_t)off*4; }
    else if (i < 4751360){ off = i-4620288; s = mo; d = MOB  + (size_t)off*4; }
    else if (i < 6193152){ off = i-4751360; s = f1;
      int row = off >> 9, c4 = off & 511;
      d = FFW + ((size_t)row*2)*2048 + c4*4; }
    else if (i < 7634944){ off = i-6193152; s = f2;
      int row = off >> 9, c4 = off & 511;
      d = FFW + ((size_t)row*2 + 1)*2048 + c4*4; }
    else if (i < 9076736){ off = i-7634944; s = fo; d = FFOB + (size_t)off*4; }
    else if (i < 9093120){ off = i-9076736; s = ak; d = AKB  + (size_t)off*4; }
    else return;
    float4 v = ((const float4*)s)[off];
    ushort4 o;
    o.x = f2b(v.x); o.y = f2b(v.y); o.z = f2b(v.z); o.w = f2b(v.w);
    *(ushort4*)d = o;
  } else if (bid < 35776){
    int i = bid - 35520, j = tid;
    MKTB[(size_t)j*256 + i] = f2b(mk[(size_t)i*256 + j]);
  } else if (bid < 35840){
    int idx = (bid - 35776)*256 + tid;   // 16384
    int pos = idx >> 7, j = idx & 127;
    float inv = powf(10000.f, -(float)j/128.f);
    float a = (float)pos * inv;
    TR[idx] = make_float2(cosf(a), sinf(a));
  } else {
    int row = bid - 35840;
    const float* xr = xsrc + (size_t)row*2048;
    float ss = 0.f;
    for (int j = tid; j < 2048; j += 256){ float v = xr[j]; ss += v*v; }
    __shared__ float red[256];
    red[tid] = ss; __syncthreads();
    for (int s = 128; s > 0; s >>= 1){ if (tid < s) red[tid] += red[tid+s]; __syncthreads(); }
    float scale = g1[0] / (sqrtf(red[0]) + 1e-8f);
    unsigned short* orow = XNb + (size_t)row*2048;
    for (int j4 = tid; j4 < 512; j4 += 256){
      float4 v = *(const float4*)(xr + j4*4);
      ushort4 o;
      o.x = f2b(v.x*scale); o.y = f2b(v.y*scale); o.z = f2b(v.z*scale); o.w = f2b(v.w*scale);
      ((ushort4*)orow)[j4] = o;
    }
  }
}

// ---------------- scale norm -> bf16 (for XS2) ----------------------------------
__global__ __launch_bounds__(256) void k_scalenorm_b(const float* __restrict__ x,
    const float* __restrict__ g, unsigned short* __restrict__ ob){
  int row = blockIdx.x, tid = threadIdx.x;
  const float* xr = x + (size_t)row*2048;
  float ss = 0.f;
  for (int j = tid; j < 2048; j += 256){ float v = xr[j]; ss += v*v; }
  __shared__ float red[256];
  red[tid] = ss; __syncthreads();
  for (int s = 128; s > 0; s >>= 1){ if (tid < s) red[tid] += red[tid+s]; __syncthreads(); }
  float scale = g[0] / (sqrtf(red[0]) + 1e-8f);
  unsigned short* orow = ob + (size_t)row*2048;
  for (int j4 = tid; j4 < 512; j4 += 256){
    float4 v = *(const float4*)(xr + j4*4);
    ushort4 o;
    o.x = f2b(v.x*scale); o.y = f2b(v.y*scale); o.z = f2b(v.z*scale); o.w = f2b(v.w*scale);
    ((ushort4*)orow)[j4] = o;
  }
}

// ---------------- pipelined bf16 MFMA GEMM (128x128): C = A @ B^T ---------------
// 128x128 tile, BK=32, 4 waves (64x64 each), 3 LDS buffers, counted vmcnt.
__global__ __launch_bounds__(256) void k_gemm_p(
    const unsigned short* __restrict__ A, int lda,
    const unsigned short* __restrict__ B,
    float* __restrict__ C, unsigned short* __restrict__ Cb,
    int N, int K, int ldc, int epi,
    const float* __restrict__ add,
    const unsigned short* __restrict__ gate, int gate_ld,
    const unsigned short* A2, const unsigned short* B2, float* C2){
  __shared__ unsigned short LDSu[24576];     // 48 KB
  int tid = threadIdx.x;
  int w = tid >> 6, l = tid & 63;
  int bi = blockIdx.y, bj = blockIdx.x;
  const unsigned short* Ap = A; const unsigned short* Bp = B; float* Cp = C;
  if (blockIdx.z){ Ap = A2; Bp = B2; Cp = C2; }
  int m0 = bi*128, n0 = bj*128;
  int wr = w >> 1, wc = w & 1;

  f32x4 acc[4][4];
#pragma unroll
  for (int i=0;i<4;++i)
#pragma unroll
    for (int j=0;j<4;++j){ f32x4 z = {0.f,0.f,0.f,0.f}; acc[i][j] = z; }

  const int r0 = tid >> 2;
  const int gsrc8 = (((tid&3) ^ ((tid>>3)&3)) * 8);

  auto stage = [&](int bs, int kt){
    unsigned short* db = LDSu + bs*8192;
    const unsigned short* ap0 = Ap + (size_t)(m0 + r0)*lda      + kt*32 + gsrc8;
    const unsigned short* ap1 = Ap + (size_t)(m0 + 64 + r0)*lda + kt*32 + gsrc8;
    const unsigned short* bp0 = Bp + (size_t)(n0 + r0)*K        + kt*32 + gsrc8;
    const unsigned short* bp1 = Bp + (size_t)(n0 + 64 + r0)*K   + kt*32 + gsrc8;
    __builtin_amdgcn_global_load_lds((const AS1 void*)ap0, (AS3 void*)(db + tid*8),        16, 0, 0);
    __builtin_amdgcn_global_load_lds((const AS1 void*)ap1, (AS3 void*)(db + 2048 + tid*8), 16, 0, 0);
    __builtin_amdgcn_global_load_lds((const AS1 void*)bp0, (AS3 void*)(db + 4096 + tid*8), 16, 0, 0);
    __builtin_amdgcn_global_load_lds((const AS1 void*)bp1, (AS3 void*)(db + 6144 + tid*8), 16, 0, 0);
  };

  const int nt = K >> 5;
  stage(0, 0);
  stage(1, 1);
  asm volatile("s_waitcnt vmcnt(4)" ::: "memory");
  __builtin_amdgcn_s_barrier();

  const int lr = l & 15;
  const int gsw = (((l>>4) ^ ((l>>1)&3)) * 8);
  const int aoff = (wr*64 + lr)*32 + gsw;
  const int boff = 4096 + (wc*64 + lr)*32 + gsw;

  int cur = 0;
  for (int t = 0; t < nt; ++t){
    if (t + 2 < nt) stage((t+2)%3, t+2);
    const unsigned short* Tb = LDSu + cur*8192;
    bhalf8 af[4], bfr[4];
#pragma unroll
    for (int m=0;m<4;++m) af[m]  = *(const bhalf8*)(Tb + aoff + m*512);
#pragma unroll
    for (int n=0;n<4;++n) bfr[n] = *(const bhalf8*)(Tb + boff + n*512);
    __builtin_amdgcn_s_setprio(1);
#pragma unroll
    for (int m=0;m<4;++m)
#pragma unroll
      for (int n=0;n<4;++n)
        acc[m][n] = __builtin_amdgcn_mfma_f32_16x16x32_bf16(af[m], bfr[n], acc[m][n], 0, 0, 0);
    __builtin_amdgcn_s_setprio(0);
    if (t + 1 < nt){
      if (t + 2 < nt){ asm volatile("s_waitcnt vmcnt(4)" ::: "memory"); }
      else           { asm volatile("s_waitcnt vmcnt(0)" ::: "memory"); }
      __builtin_amdgcn_s_barrier();
      cur = (cur == 2) ? 0 : cur + 1;
    }
  }

#pragma unroll
  for (int m=0;m<4;++m){
    int rowb = m0 + wr*64 + m*16 + ((l>>4)<<2);
#pragma unroll
    for (int r=0;r<4;++r){
      int row = rowb + r;
      size_t rbase = (size_t)row*ldc;
      size_t gbase = (size_t)row*gate_ld;
#pragma unroll
      for (int n=0;n<4;++n){
        int col = n0 + wc*64 + n*16 + (l&15);
        float v = acc[m][n][r];
        if (add) v += add[rbase + col];
        if (epi == 2) v *= sigmoidf_(b2f(gate[gbase + col]));
        if (epi == 3) Cb[rbase + col] = f2b(v);
        else          Cp[rbase + col] = v;
      }
    }
  }
}

// ---------------- BN=64 pipelined GEMM: C = A @ B^T + add (f32 out) -------------
__global__ __launch_bounds__(256) void k_gemm_p64(
    const unsigned short* __restrict__ A, int lda,
    const unsigned short* __restrict__ B,
    float* __restrict__ C, int K, int ldc,
    const float* __restrict__ add){
  __shared__ unsigned short LDSu[18432];     // 36 KB
  int tid = threadIdx.x;
  int w = tid >> 6, l = tid & 63;
  int bi = blockIdx.y, bj = blockIdx.x;
  int m0 = bi*128, n0 = bj*64;
  int wr = w >> 1, wc = w & 1;

  f32x4 acc[4][2];
#pragma unroll
  for (int i=0;i<4;++i)
#pragma unroll
    for (int j=0;j<2;++j){ f32x4 z = {0.f,0.f,0.f,0.f}; acc[i][j] = z; }

  const int r0 = tid >> 2;
  const int gsrc8 = (((tid&3) ^ ((tid>>3)&3)) * 8);

  auto stage = [&](int bs, int kt){
    unsigned short* db = LDSu + bs*6144;
    const unsigned short* ap0 = A + (size_t)(m0 + r0)*lda      + kt*32 + gsrc8;
    const unsigned short* ap1 = A + (size_t)(m0 + 64 + r0)*lda + kt*32 + gsrc8;
    const unsigned short* bp0 = B + (size_t)(n0 + r0)*K        + kt*32 + gsrc8;
    __builtin_amdgcn_global_load_lds((const AS1 void*)ap0, (AS3 void*)(db + tid*8),        16, 0, 0);
    __builtin_amdgcn_global_load_lds((const AS1 void*)ap1, (AS3 void*)(db + 2048 + tid*8), 16, 0, 0);
    __builtin_amdgcn_global_load_lds((const AS1 void*)bp0, (AS3 void*)(db + 4096 + tid*8), 16, 0, 0);
  };

  const int nt = K >> 5;
  stage(0, 0);
  stage(1, 1);
  asm volatile("s_waitcnt vmcnt(3)" ::: "memory");
  __builtin_amdgcn_s_barrier();

  const int lr = l & 15;
  const int gsw = (((l>>4) ^ ((l>>1)&3)) * 8);
  const int aoff = (wr*64 + lr)*32 + gsw;
  const int boff = 4096 + (wc*32 + lr)*32 + gsw;

  int cur = 0;
  for (int t = 0; t < nt; ++t){
    if (t + 2 < nt) stage((t+2)%3, t+2);
    const unsigned short* Tb = LDSu + cur*6144;
    bhalf8 af[4], bfr[2];
#pragma unroll
    for (int m=0;m<4;++m) af[m]  = *(const bhalf8*)(Tb + aoff + m*512);
#pragma unroll
    for (int n=0;n<2;++n) bfr[n] = *(const bhalf8*)(Tb + boff + n*512);
    __builtin_amdgcn_s_setprio(1);
#pragma unroll
    for (int m=0;m<4;++m)
#pragma unroll
      for (int n=0;n<2;++n)
        acc[m][n] = __builtin_amdgcn_mfma_f32_16x16x32_bf16(af[m], bfr[n], acc[m][n], 0, 0, 0);
    __builtin_amdgcn_s_setprio(0);
    if (t + 1 < nt){
      if (t + 2 < nt){ asm volatile("s_waitcnt vmcnt(3)" ::: "memory"); }
      else           { asm volatile("s_waitcnt vmcnt(0)" ::: "memory"); }
      __builtin_amdgcn_s_barrier();
      cur = (cur == 2) ? 0 : cur + 1;
    }
  }

#pragma unroll
  for (int m=0;m<4;++m){
    int rowb = m0 + wr*64 + m*16 + ((l>>4)<<2);
#pragma unroll
    for (int r=0;r<4;++r){
      int row = rowb + r;
      size_t rbase = (size_t)row*ldc;
#pragma unroll
      for (int n=0;n<2;++n){
        int col = n0 + wc*32 + n*16 + (l&15);
        C[rbase + col] = acc[m][n][r] + add[rbase + col];
      }
    }
  }
}

// ---------------- BN=64 fused AO+MO GEMM -> XS2 ---------------------------------
__global__ __launch_bounds__(256) void k_gemm_fuse2_64(
    const unsigned short* __restrict__ A,  const unsigned short* __restrict__ B,
    const unsigned short* __restrict__ A2, const unsigned short* __restrict__ B2,
    const unsigned short* __restrict__ gate1, const unsigned short* __restrict__ gate2,
    const float* __restrict__ xs, float* __restrict__ XS2){
  __shared__ unsigned short LDSu[18432];
  int tid = threadIdx.x;
  int w = tid >> 6, l = tid & 63;
  int bi = blockIdx.y, bj = blockIdx.x;
  int m0 = bi*128, n0 = bj*64;
  int wr = w >> 1, wc = w & 1;

  f32x4 acc[4][2], acc2[4][2];
#pragma unroll
  for (int i=0;i<4;++i)
#pragma unroll
    for (int j=0;j<2;++j){ f32x4 z = {0.f,0.f,0.f,0.f}; acc[i][j] = z; acc2[i][j] = z; }

  const int r0 = tid >> 2;
  const int gsrc8 = (((tid&3) ^ ((tid>>3)&3)) * 8);

  auto stage = [&](int bs, int kt, const unsigned short* Ap, int lda,
                   const unsigned short* Bp, int ldb){
    unsigned short* db = LDSu + bs*6144;
    const unsigned short* ap0 = Ap + (size_t)(m0 + r0)*lda      + kt*32 + gsrc8;
    const unsigned short* ap1 = Ap + (size_t)(m0 + 64 + r0)*lda + kt*32 + gsrc8;
    const unsigned short* bp0 = Bp + (size_t)(n0 + r0)*ldb      + kt*32 + gsrc8;
    __builtin_amdgcn_global_load_lds((const AS1 void*)ap0, (AS3 void*)(db + tid*8),        16, 0, 0);
    __builtin_amdgcn_global_load_lds((const AS1 void*)ap1, (AS3 void*)(db + 2048 + tid*8), 16, 0, 0);
    __builtin_amdgcn_global_load_lds((const AS1 void*)bp0, (AS3 void*)(db + 4096 + tid*8), 16, 0, 0);
  };

  const int lr = l & 15;
  const int gsw = (((l>>4) ^ ((l>>1)&3)) * 8);
  const int aoff = (wr*64 + lr)*32 + gsw;
  const int boff = 4096 + (wc*32 + lr)*32 + gsw;

  {
    const int nt = 64;
    stage(0, 0, A, 2048, B, 2048);
    stage(1, 1, A, 2048, B, 2048);
    asm volatile("s_waitcnt vmcnt(3)" ::: "memory");
    __builtin_amdgcn_s_barrier();
    int cur = 0;
    for (int t = 0; t < nt; ++t){
      if (t + 2 < nt) stage((t+2)%3, t+2, A, 2048, B, 2048);
      const unsigned short* Tb = LDSu + cur*6144;
      bhalf8 af[4], bfr[2];
#pragma unroll
      for (int m=0;m<4;++m) af[m]  = *(const bhalf8*)(Tb + aoff + m*512);
#pragma unroll
      for (int n=0;n<2;++n) bfr[n] = *(const bhalf8*)(Tb + boff + n*512);
      __builtin_amdgcn_s_setprio(1);
#pragma unroll
      for (int m=0;m<4;++m)
#pragma unroll
        for (int n=0;n<2;++n)
          acc[m][n] = __builtin_amdgcn_mfma_f32_16x16x32_bf16(af[m], bfr[n], acc[m][n], 0, 0, 0);
      __builtin_amdgcn_s_setprio(0);
      if (t + 1 < nt){
        if (t + 2 < nt){ asm volatile("s_waitcnt vmcnt(3)" ::: "memory"); }
        else           { asm volatile("s_waitcnt vmcnt(0)" ::: "memory"); }
        __builtin_amdgcn_s_barrier();
        cur = (cur == 2) ? 0 : cur + 1;
      }
    }
  }
  __syncthreads();

  {
    const int nt = 8;
    stage(0, 0, A2, 256, B2, 256);
    stage(1, 1, A2, 256, B2, 256);
    asm volatile("s_waitcnt vmcnt(3)" ::: "memory");
    __builtin_amdgcn_s_barrier();
    int cur = 0;
    for (int t = 0; t < nt; ++t){
      if (t + 2 < nt) stage((t+2)%3, t+2, A2, 256, B2, 256);
      const unsigned short* Tb = LDSu + cur*6144;
      bhalf8 af[4], bfr[2];
#pragma unroll
      for (int m=0;m<4;++m) af[m]  = *(const bhalf8*)(Tb + aoff + m*512);
#pragma unroll
      for (int n=0;n<2;++n) bfr[n] = *(const bhalf8*)(Tb + boff + n*512);
      __builtin_amdgcn_s_setprio(1);
#pragma unroll
      for (int m=0;m<4;++m)
#pragma unroll
        for (int n=0;n<2;++n)
          acc2[m][n] = __builtin_amdgcn_mfma_f32_16x16x32_bf16(af[m], bfr[n], acc2[m][n], 0, 0, 0);
      __builtin_amdgcn_s_setprio(0);
      if (t + 1 < nt){
        if (t + 2 < nt){ asm volatile("s_waitcnt vmcnt(3)" ::: "memory"); }
        else           { asm volatile("s_waitcnt vmcnt(0)" ::: "memory"); }
        __builtin_amdgcn_s_barrier();
        cur = (cur == 2) ? 0 : cur + 1;
      }
    }
  }

#pragma unroll
  for (int m=0;m<4;++m){
    int rowb = m0 + wr*64 + m*16 + ((l>>4)<<2);
#pragma unroll
    for (int r=0;r<4;++r){
      int row = rowb + r;
      size_t gb = (size_t)row*CC_LD;
      size_t rb = (size_t)row*2048;
#pragma unroll
      for (int n=0;n<2;++n){
        int col = n0 + wc*32 + n*16 + (l&15);
        float v = acc[m][n][r]*sigmoidf_(b2f(gate1[gb + col]))
                + acc2[m][n][r]*sigmoidf_(b2f(gate2[gb + col]))
                + xs[rb + col];
        XS2[rb + col] = v;
      }
    }
  }
}

// ---------------- SiLU-pair GEMM (FF-in) ----------------------------------------
__global__ __launch_bounds__(256) void k_gemm_silu(
    const unsigned short* __restrict__ A, int lda,
    const unsigned short* __restrict__ B,
    unsigned short* __restrict__ Cb, int K, int out_ld){
  __shared__ unsigned short LDSu[24576];
  int tid = threadIdx.x;
  int w = tid >> 6, l = tid & 63;
  int bi = blockIdx.y, bj = blockIdx.x;
  int m0 = bi*128, n0 = bj*128;
  int wr = w >> 1, wc = w & 1;

  f32x4 acc[4][4];
#pragma unroll
  for (int i=0;i<4;++i)
#pragma unroll
    for (int j=0;j<4;++j){ f32x4 z = {0.f,0.f,0.f,0.f}; acc[i][j] = z; }

  const int r0 = tid >> 2;
  const int gsrc8 = (((tid&3) ^ ((tid>>3)&3)) * 8);

  auto stage = [&](int bs, int kt){
    unsigned short* db = LDSu + bs*8192;
    const unsigned short* ap0 = A + (size_t)(m0 + r0)*lda      + kt*32 + gsrc8;
    const unsigned short* ap1 = A + (size_t)(m0 + 64 + r0)*lda + kt*32 + gsrc8;
    const unsigned short* bp0 = B + (size_t)(n0 + r0)*K        + kt*32 + gsrc8;
    const unsigned short* bp1 = B + (size_t)(n0 + 64 + r0)*K   + kt*32 + gsrc8;
    __builtin_amdgcn_global_load_lds((const AS1 void*)ap0, (AS3 void*)(db + tid*8),        16, 0, 0);
    __builtin_amdgcn_global_load_lds((const AS1 void*)ap1, (AS3 void*)(db + 2048 + tid*8), 16, 0, 0);
    __builtin_amdgcn_global_load_lds((const AS1 void*)bp0, (AS3 void*)(db + 4096 + tid*8), 16, 0, 0);
    __builtin_amdgcn_global_load_lds((const AS1 void*)bp1, (AS3 void*)(db + 6144 + tid*8), 16, 0, 0);
  };

  const int nt = K >> 5;
  stage(0, 0);
  stage(1, 1);
  asm volatile("s_waitcnt vmcnt(4)" ::: "memory");
  __builtin_amdgcn_s_barrier();

  const int lr = l & 15;
  const int gsw = (((l>>4) ^ ((l>>1)&3)) * 8);
  const int aoff = (wr*64 + lr)*32 + gsw;
  const int boff = 4096 + (wc*64 + lr)*32 + gsw;

  int cur = 0;
  for (int t = 0; t < nt; ++t){
    if (t + 2 < nt) stage((t+2)%3, t+2);
    const unsigned short* Tb = LDSu + cur*8192;
    bhalf8 af[4], bfr[4];
#pragma unroll
    for (int m=0;m<4;++m) af[m]  = *(const bhalf8*)(Tb + aoff + m*512);
#pragma unroll
    for (int n=0;n<4;++n) bfr[n] = *(const bhalf8*)(Tb + boff + n*512);
    __builtin_amdgcn_s_setprio(1);
#pragma unroll
    for (int m=0;m<4;++m)
#pragma unroll
      for (int n=0;n<4;++n)
        acc[m][n] = __builtin_amdgcn_mfma_f32_16x16x32_bf16(af[m], bfr[n], acc[m][n], 0, 0, 0);
    __builtin_amdgcn_s_setprio(0);
    if (t + 1 < nt){
      if (t + 2 < nt){ asm volatile("s_waitcnt vmcnt(4)" ::: "memory"); }
      else           { asm volatile("s_waitcnt vmcnt(0)" ::: "memory"); }
      __builtin_amdgcn_s_barrier();
      cur = (cur == 2) ? 0 : cur + 1;
    }
  }

#pragma unroll
  for (int m=0;m<4;++m){
    int rowb = m0 + wr*64 + m*16 + ((l>>4)<<2);
#pragma unroll
    for (int r=0;r<4;++r){
      int row = rowb + r;
      size_t gbase = (size_t)row*out_ld;
#pragma unroll
      for (int n=0;n<4;++n){
        int col = n0 + wc*64 + n*16 + (l&15);
        float v = acc[m][n][r];
        float o = __shfl_xor(v, 1);
        if ((l & 1) == 0)
          Cb[gbase + (col>>1)] = f2b(v*sigmoidf_(v)*o);
      }
    }
  }
}

// ---------------- fused attention scores+softmax (MFMA) -------------------------
__global__ __launch_bounds__(256) void k_attn_scores_mfma(
    const unsigned short* __restrict__ CCqb, const float* __restrict__ K0,
    const float2* __restrict__ TR, unsigned short* __restrict__ P){
  __shared__ unsigned short Ks[128*256];   // 64 KB
  int c = blockIdx.x, tid = threadIdx.x;
  for (int it = 0; it < 16; ++it){
    int id = tid + it*256;          // 0..4095
    int m = id >> 5;                // key row 0..127, rope pos = m
    int cs = (id & 31) * 8;         // f32 col start
    float v[8];
    if (c == 0 && m < 64){
#pragma unroll
      for (int u=0;u<8;++u) v[u] = 0.f;
    } else {
      int gr = (c-1)*64 + m;
      const float* kr = K0 + (size_t)gr*256 + cs;
      float4 x0 = *(const float4*)kr, x1 = *(const float4*)(kr+4);
      v[0]=x0.x; v[1]=x0.y; v[2]=x0.z; v[3]=x0.w;
      v[4]=x1.x; v[5]=x1.y; v[6]=x1.z; v[7]=x1.w;
#pragma unroll
      for (int p2=0;p2<4;++p2){
        float2 t = TR[m*128 + (cs>>1) + p2];
        float e = v[2*p2], o = v[2*p2+1];
        v[2*p2]   = e*t.x - o*t.y;
        v[2*p2+1] = o*t.x + e*t.y;
      }
    }
    unsigned short pk[8];
#pragma unroll
    for (int u=0;u<8;++u) pk[u] = f2b(v[u]);
    int byte = m*512 + ((cs*2) ^ ((m&7)<<4));
    *(bhalf8*)((char*)&Ks[0] + byte) = *(const bhalf8*)pk;
  }
  __syncthreads();

  int w = tid >> 6, l = tid & 63;
  int lr = l & 15, lkg = l >> 4;
  f32x4 acc[8];
#pragma unroll
  for (int n=0;n<8;++n){ f32x4 z = {0.f,0.f,0.f,0.f}; acc[n] = z; }

  int iq = w*16 + lr;
  const unsigned short* qbase = CCqb + (size_t)(c*64 + iq)*CC_LD;
  int pos = 64 + iq;

  for (int kt = 0; kt < 8; ++kt){
    int k0c = kt*32 + lkg*8;
    bhalf8 q8 = *(const bhalf8*)(qbase + k0c);
    float v[8];
#pragma unroll
    for (int u=0;u<8;++u) v[u] = b2f((unsigned short)(((short*)&q8)[u]));
#pragma unroll
    for (int p2=0;p2<4;++p2){
      float2 t = TR[pos*128 + (k0c>>1) + p2];
      float e = v[2*p2], o = v[2*p2+1];
      v[2*p2]   = e*t.x - o*t.y;
      v[2*p2+1] = o*t.x + e*t.y;
    }
    unsigned short pk[8];
#pragma unroll
    for (int u=0;u<8;++u) pk[u] = f2b(v[u]);
    bhalf8 af = *(const bhalf8*)pk;
#pragma unroll
    for (int n=0;n<8;++n){
      int m = n*16 + lr;
      int byte = m*512 + ((k0c*2) ^ ((m&7)<<4));
      bhalf8 bf = *(const bhalf8*)((const char*)&Ks[0] + byte);
      acc[n] = __builtin_amdgcn_mfma_f32_16x16x32_bf16(af, bf, acc[n], 0, 0, 0);
    }
  }

  int i0 = w*16 + lkg*4;
  float mx[4] = {-1e30f,-1e30f,-1e30f,-1e30f};
  float sm[4] = {0.f,0.f,0.f,0.f};
#pragma unroll
  for (int n=0;n<8;++n){
    int col = n*16 + lr;
#pragma unroll
    for (int r=0;r<4;++r){
      float vv = acc[n][r] * (1.f/16.f);
      if (col > i0 + r + 64) vv = -1e30f;
      acc[n][r] = vv;
      mx[r] = fmaxf(mx[r], vv);
    }
  }
#pragma unroll
  for (int s=1; s<16; s<<=1)
#pragma unroll
    for (int r=0;r<4;++r) mx[r] = fmaxf(mx[r], __shfl_xor(mx[r], s));
#pragma unroll
  for (int n=0;n<8;++n)
#pragma unroll
    for (int r=0;r<4;++r){
      float e = expf(acc[n][r] - mx[r]);
      acc[n][r] = e; sm[r] += e;
    }
#pragma unroll
  for (int s=1; s<16; s<<=1)
#pragma unroll
    for (int r=0;r<4;++r) sm[r] += __shfl_xor(sm[r], s);
  float rcp[4];
#pragma unroll
  for (int r=0;r<4;++r) rcp[r] = 1.f/sm[r];

  unsigned short* Pr = P + (size_t)c*8192;
#pragma unroll
  for (int n=0;n<8;++n){
    int col = n*16 + lr;
#pragma unroll
    for (int r=0;r<4;++r)
      Pr[(i0+r)*128 + col] = f2b(acc[n][r]*rcp[r]);
  }
}

// ---------------- MFMA PV: Y[c*64+i, ct*128+:] = P[c] @ V2[c] -------------------
__global__ __launch_bounds__(256) void k_attn_pv_mfma(
    const unsigned short* __restrict__ P, const unsigned short* __restrict__ Vb, int vld,
    unsigned short* __restrict__ Y){
  __shared__ unsigned short Vt[128*128];   // [col][k] swizzled, 32 KB
  int ct = blockIdx.x, c = blockIdx.y, tid = threadIdx.x;
  {
    int k = tid >> 1;               // V2 row 0..127
    int ch = (tid & 1) * 64;        // col half
    if (c == 0 && k < 64){
      for (int u=0; u<64; ++u){
        int col = ch + u;
        int byte = col*256 + ((k*2) ^ ((col&7)<<4));
        *(unsigned short*)((char*)&Vt[0] + byte) = 0;
      }
    } else {
      int gr = (c-1)*64 + k;
      const unsigned short* vr = Vb + (size_t)gr*vld + ct*128 + ch;
      for (int u8=0; u8<8; ++u8){
        bhalf8 x = *(const bhalf8*)(vr + u8*8);
#pragma unroll
        for (int u=0;u<8;++u){
          int col = ch + u8*8 + u;
          int byte = col*256 + ((k*2) ^ ((col&7)<<4));
          *(unsigned short*)((char*)&Vt[0] + byte) = (unsigned short)(((short*)&x)[u]);
        }
      }
    }
  }
  __syncthreads();
  int w = tid >> 6, l = tid & 63, lr = l & 15, lkg = l >> 4;
  f32x4 acc[8];
#pragma unroll
  for (int n=0;n<8;++n){ f32x4 z = {0.f,0.f,0.f,0.f}; acc[n] = z; }
  const unsigned short* Pr = P + (size_t)c*8192;
  for (int kt=0; kt<4; ++kt){
    int kb = kt*32 + lkg*8;
    bhalf8 af = *(const bhalf8*)(Pr + (w*16 + lr)*128 + kb);
#pragma unroll
    for (int n=0;n<8;++n){
      int col = n*16 + lr;
      int byte = col*256 + ((kb*2) ^ ((col&7)<<4));
      bhalf8 bf = *(const bhalf8*)((const char*)&Vt[0] + byte);
      acc[n] = __builtin_amdgcn_mfma_f32_16x16x32_bf16(af, bf, acc[n], 0, 0, 0);
    }
  }
  int row0 = c*64 + w*16 + lkg*4;
#pragma unroll
  for (int n=0;n<8;++n){
    int col = ct*128 + n*16 + lr;
#pragma unroll
    for (int r=0;r<4;++r)
      Y[(size_t)(row0+r)*2048 + col] = f2b(acc[n][r]);
  }
}

// ---------------- mem scan, chunk=16, 8 memories per block ----------------------
__global__ __launch_bounds__(256) void k_scan1(const unsigned short* __restrict__ CC,
    const float* __restrict__ beta_p, const float* __restrict__ decay_p,
    float* __restrict__ CP, float* __restrict__ CQ){
  int c = blockIdx.x, mg = blockIdx.y, d = threadIdx.x;
  __shared__ float Fs[128];
  if (threadIdx.x < 128){
    int s = threadIdx.x >> 3, j = threadIdx.x & 7;
    Fs[threadIdx.x] = sigmoidf_(b2f(CC[(size_t)(c*16+s)*CC_LD + COL_FG + mg*8 + j]));
  }
  __syncthreads();
  float beta[8], gamma[8], Pa[8], Qa[8];
#pragma unroll
  for (int j=0;j<8;++j){
    int m = mg*8+j;
    beta[j]  = sigmoidf_(beta_p[m*256+d]);
    gamma[j] = (d < 192) ? 1.f : sigmoidf_(decay_p[m*64 + (d-192)]);
    Pa[j] = 1.f; Qa[j] = 0.f;
  }
  for (int s = 0; s < 16; ++s){
    float vm = b2f(CC[(size_t)(c*16+s)*CC_LD + COL_VM + d]);
#pragma unroll
    for (int j=0;j<8;++j){
      float f = Fs[s*8+j];
      float w = (1.f - f*beta[j])*gamma[j];
      Pa[j] *= w;
      Qa[j] = w*Qa[j] + f*vm;
    }
  }
#pragma unroll
  for (int j=0;j<8;++j){
    size_t idx = ((size_t)c*64 + mg*8 + j)*256 + d;
    CP[idx] = Pa[j]; CQ[idx] = Qa[j];
  }
}

__global__ __launch_bounds__(256) void k_scan2(const float* __restrict__ CP,
    const float* __restrict__ CQ, float* __restrict__ SIN){
  int m = blockIdx.x, d = threadIdx.x;
  float S = 0.f;
  for (int c = 0; c < 128; ++c){
    size_t idx = ((size_t)c*64 + m)*256 + d;
    SIN[idx] = S;
    S = CP[idx]*S + CQ[idx];
  }
}

__global__ __launch_bounds__(256) void k_scan3(const unsigned short* __restrict__ CC,
    const float* __restrict__ beta_p, const float* __restrict__ decay_p,
    const float* __restrict__ SIN, unsigned short* __restrict__ MEMS){
  int c = blockIdx.x, mg = blockIdx.y, d = threadIdx.x;
  __shared__ float Fs[128];
  if (threadIdx.x < 128){
    int s = threadIdx.x >> 3, j = threadIdx.x & 7;
    Fs[threadIdx.x] = sigmoidf_(b2f(CC[(size_t)(c*16+s)*CC_LD + COL_FG + mg*8 + j]));
  }
  __syncthreads();
  float beta[8], gamma[8], S[8];
#pragma unroll
  for (int j=0;j<8;++j){
    int m = mg*8+j;
    beta[j]  = sigmoidf_(beta_p[m*256+d]);
    gamma[j] = (d < 192) ? 1.f : sigmoidf_(decay_p[m*64 + (d-192)]);
    S[j] = SIN[((size_t)c*64 + m)*256 + d];
  }
  for (int s = 0; s < 16; ++s){
    float vm = b2f(CC[(size_t)(c*16+s)*CC_LD + COL_VM + d]);
    size_t tb = (size_t)(c*16+s)*64;
#pragma unroll
    for (int j=0;j<8;++j){
      float f = Fs[s*8+j];
      float w = (1.f - f*beta[j])*gamma[j];
      S[j] = w*S[j] + f*vm;
      MEMS[(tb + mg*8 + j)*256 + d] = f2b(S[j]);
    }
  }
}

// ---------------- mem readout (wave-parallel softmax, vectorized pass 2) --------
__global__ __launch_bounds__(256) void k_memread(const unsigned short* __restrict__ MEMS,
    const float* __restrict__ QH, const unsigned short* __restrict__ QMs, int qm_ld,
    const float* __restrict__ L, unsigned short* __restrict__ YMb){
  int t = blockIdx.x, tid = threadIdx.x;
  int wave = tid >> 6, lane = tid & 63;
  __shared__ float anorm[64];
  __shared__ float red2[4][64][4];
  const unsigned short* Mt = MEMS + (size_t)t*16384;
  float4 qh4 = *(const float4*)(QH + (size_t)t*256 + lane*4);
  ushort4 qmu = *(const ushort4*)(QMs + (size_t)t*qm_ld + lane*4);
  float qm0 = b2f(qmu.x), qm1 = b2f(qmu.y), qm2 = b2f(qmu.z), qm3 = b2f(qmu.w);
  for (int mi = 0; mi < 16; ++mi){
    int m = wave*16 + mi;
    ushort4 su = *(const ushort4*)(Mt + m*256 + lane*4);
    float4 l4 = *(const float4*)(L + (size_t)m*256 + lane*4);
    float p = b2f(su.x)*qh4.x + b2f(su.y)*qh4.y + b2f(su.z)*qh4.z + b2f(su.w)*qh4.w
            + l4.x*qm0 + l4.y*qm1 + l4.z*qm2 + l4.w*qm3;
#pragma unroll
    for (int off = 32; off > 0; off >>= 1) p += __shfl_down(p, off);
    if (lane == 0) anorm[m] = p * (1.f/16.f);
  }
  __syncthreads();
  if (tid < 64){
    float v = anorm[tid];
    float mx = v;
#pragma unroll
    for (int off = 32; off > 0; off >>= 1) mx = fmaxf(mx, __shfl_xor(mx, off));
    float e = expf(v - mx);
    float s = e;
#pragma unroll
    for (int off = 32; off > 0; off >>= 1) s += __shfl_xor(s, off);
    anorm[tid] = e / s;
  }
  __syncthreads();
  int mq = tid >> 6, dq = tid & 63;
  float a0=0.f, a1=0.f, a2=0.f, a3=0.f;
#pragma unroll
  for (int mi = 0; mi < 16; ++mi){
    int m = mq*16 + mi;
    ushort4 su = *(const ushort4*)(Mt + m*256 + dq*4);
    float wgt = anorm[m];
    a0 += wgt*b2f(su.x); a1 += wgt*b2f(su.y);
    a2 += wgt*b2f(su.z); a3 += wgt*b2f(su.w);
  }
  red2[mq][dq][0]=a0; red2[mq][dq][1]=a1; red2[mq][dq][2]=a2; red2[mq][dq][3]=a3;
  __syncthreads();
  if (tid < 64){
    float r0=0.f, r1=0.f, r2=0.f, r3=0.f;
#pragma unroll
    for (int g=0; g<4; ++g){
      r0 += red2[g][tid][0]; r1 += red2[g][tid][1];
      r2 += red2[g][tid][2]; r3 += red2[g][tid][3];
    }
    ushort4 o;
    o.x = f2b(r0); o.y = f2b(r1); o.z = f2b(r2); o.w = f2b(r3);
    *(ushort4*)(YMb + (size_t)t*256 + tid*4) = o;
  }
}

// ---------------- launch ---------------------------------------------------------
extern "C" void kernel_launch(void* const* d_in, const int* in_sizes, int n_in,
                              void* d_out, int out_size, void* d_ws, size_t ws_size,
                              hipStream_t stream){
  const float* xs        = (const float*)d_in[0];
  const float* attn_q    = (const float*)d_in[1];
  const float* attn_k    = (const float*)d_in[2];
  const float* attn_v    = (const float*)d_in[3];
  const float* attn_o    = (const float*)d_in[4];
  const float* attn_r    = (const float*)d_in[5];
  const float* mem_f     = (const float*)d_in[6];
  const float* mem_q     = (const float*)d_in[7];
  const float* mem_k     = (const float*)d_in[8];
  const float* mem_v     = (const float*)d_in[9];
  const float* mem_o     = (const float*)d_in[10];
  const float* mem_r     = (const float*)d_in[11];
  const float* mem_beta  = (const float*)d_in[12];
  const float* mem_decay = (const float*)d_in[13];
  const float* mem_l     = (const float*)d_in[14];
  const float* ff1       = (const float*)d_in[15];
  const float* ff2       = (const float*)d_in[16];
  const float* ffo       = (const float*)d_in[17];
  const float* sn1       = (const float*)d_in[18];
  const float* sn2       = (const float*)d_in[19];
  float* out = (float*)d_out;
  float* W = (float*)d_ws;

  // ---- workspace layout (float offsets), ~246 MB ----
  unsigned short* XNb  = (unsigned short*)(W + 0);           // 2,097,152
  unsigned short* WCAT = (unsigned short*)(W + 2097152);     // 7,340,032 (7168x2048)
  unsigned short* CCb  = (unsigned short*)(W + 9437184);     // 7,340,032 (2048x7168)
  unsigned short* AOB  = (unsigned short*)(W + 16777216);    // 2,097,152
  unsigned short* MOB  = (unsigned short*)(W + 18874368);    // 262,144
  unsigned short* FFW  = (unsigned short*)(W + 19136512);    // 5,767,168 (interleaved ff1/ff2)
  unsigned short* FFOB = (unsigned short*)(W + 24903680);    // 2,883,584
  unsigned short* AKB  = (unsigned short*)(W + 27787264);    // 32,768
  unsigned short* MKTB = (unsigned short*)(W + 27820032);    // 32,768
  unsigned short* Ybb  = (unsigned short*)(W + 27852800);    // 2,097,152
  float*          XS2  = W + 34144256;                       // 4,194,304
  unsigned short* MEMSb= (unsigned short*)(W + 38338560);    // 16,777,216
  float*          CP   = W + 55115776;                       // 2,097,152 (128x64x256)
  float*          CQ   = W + 57212928;                       // 2,097,152
  float*          SIN  = W + 59310080;                       // 2,097,152
  float2*         TRIG = (float2*)(W + 61407232);            // 32,768 fl
  // aliases (sequential liveness):
  float*          K0   = W + 32768;                          // over XNb (dead after CC GEMM)
  unsigned short* P    = (unsigned short*)(W + 557056);      // over XNb
  float*          QH   = W + 688128;                         // over XNb
  unsigned short* YMb  = (unsigned short*)(W + 1212416);     // over XNb
  unsigned short* XN2b = MEMSb;                              // over MEMSb (dead after memread)
  unsigned short* H1b  = (unsigned short*)(W + 40435712);    // over MEMSb tail (2048x2816 bf16)

  dim3 blk(256);

  // ---- mega prep: converts + mem_k transpose + trig + scalenorm1 ----
  k_prep<<<dim3(37888), blk, 0, stream>>>(attn_v, attn_r, mem_r, attn_q, mem_v, mem_q,
      mem_f, attn_o, mem_o, ff1, ff2, ffo, attn_k, mem_k, xs, sn1,
      WCAT, AOB, MOB, FFW, FFOB, AKB, MKTB, TRIG, XNb);

  // ---- BIG concat GEMM (V + gates + QB + VM + QM + FG), bf16 out ----
  k_gemm_p<<<dim3(56, 16), blk, 0, stream>>>(XNb, 2048, WCAT, nullptr, CCb, CC_LD, 2048, CC_LD, 3,
      nullptr, nullptr, 0, nullptr, nullptr, nullptr);

  // ---- batched small GEMMs: z=0 -> K0 = QB @ attn_k^T ; z=1 -> QH = QM @ mem_k
  k_gemm_p<<<dim3(2, 16, 2), blk, 0, stream>>>(CCb + COL_QB, CC_LD, AKB, K0, nullptr, 256, 256, 256, 0,
      nullptr, nullptr, 0, CCb + COL_QM, MKTB, QH);

  // ---- attention scores + PV ----
  k_attn_scores_mfma<<<dim3(32), blk, 0, stream>>>(CCb + COL_QB, K0, TRIG, P);
  k_attn_pv_mfma<<<dim3(16, 32), blk, 0, stream>>>(P, CCb + COL_V, CC_LD, Ybb);

  // ---- memory branch (chunk=16 scan) ----
  k_scan1<<<dim3(128, 8), blk, 0, stream>>>(CCb, mem_beta, mem_decay, CP, CQ);
  k_scan2<<<dim3(64), blk, 0, stream>>>(CP, CQ, SIN);
  k_scan3<<<dim3(128, 8), blk, 0, stream>>>(CCb, mem_beta, mem_decay, SIN, MEMSb);
  k_memread<<<dim3(2048), blk, 0, stream>>>(MEMSb, QH, CCb + COL_QM, CC_LD, mem_l, YMb);

  // ---- fused AO+MO -> XS2 = attn_out + mem_out + xs (BN=64, 512 blocks) ----
  k_gemm_fuse2_64<<<dim3(32, 16), blk, 0, stream>>>(Ybb, AOB, YMb, MOB,
      CCb + COL_B1, CCb + COL_B2, xs, XS2);

  // ---- xn2 = scalenorm(XS2) -> bf16 ----
  k_scalenorm_b<<<dim3(2048), blk, 0, stream>>>(XS2, sn2, XN2b);

  // ---- FF: SiLU-fused GEMM -> H1b, then BN=64 out GEMM (512 blocks) ----
  k_gemm_silu<<<dim3(44, 16), blk, 0, stream>>>(XN2b, 2048, FFW, H1b, 2048, 2816);
  k_gemm_p64<<<dim3(32, 16), blk, 0, stream>>>(H1b, 2816, FFOB, out, 2816, 2048, XS2);
}

// Round 18
// 373.796 us; speedup vs baseline: 1.0822x; 1.0452x over previous
//
#include <hip/hip_runtime.h>
#include <math.h>

// RAMEN layer. Round 18: blockIdx-partitioned combo kernels to overlap the
// independent attention and scan chains ({smallGEMM||scan1}, {scores||scan2},
// {PV||scan3}). GEMM kernels byte-identical to R17 (390.7us best).
// T=2048, X_D=2048, M_D=256, M_N=64, CHUNK=64, FF_D=2816.

typedef short bhalf8 __attribute__((ext_vector_type(8)));
typedef float f32x4 __attribute__((ext_vector_type(4)));

#define CC_LD 7168
#define COL_V   0
#define COL_B1  2048
#define COL_B2  4096
#define COL_QB  6144
#define COL_VM  6400
#define COL_QM  6656
#define COL_FG  6912

#define AS1 __attribute__((address_space(1)))
#define AS3 __attribute__((address_space(3)))

__device__ __forceinline__ float sigmoidf_(float x){ return 1.0f/(1.0f+expf(-x)); }

__device__ __forceinline__ unsigned short f2b(float f){
  unsigned u = __float_as_uint(f);
  unsigned r = (u + 0x7fffu + ((u>>16)&1u)) >> 16;
  return (unsigned short)r;
}
__device__ __forceinline__ float b2f(unsigned short h){
  return __uint_as_float(((unsigned)h)<<16);
}

// ---------------- mega prep: weight converts + mem_k transpose + trig + norm ----
__global__ __launch_bounds__(256) void k_prep(
    const float* __restrict__ av, const float* __restrict__ ar, const float* __restrict__ mr,
    const float* __restrict__ aq, const float* __restrict__ mv, const float* __restrict__ mq,
    const float* __restrict__ mf, const float* __restrict__ ao, const float* __restrict__ mo,
    const float* __restrict__ f1, const float* __restrict__ f2, const float* __restrict__ fo,
    const float* __restrict__ ak, const float* __restrict__ mk,
    const float* __restrict__ xsrc, const float* __restrict__ g1,
    unsigned short* __restrict__ WCAT, unsigned short* __restrict__ AOB,
    unsigned short* __restrict__ MOB, unsigned short* __restrict__ FFW,
    unsigned short* __restrict__ FFOB, unsigned short* __restrict__ AKB,
    unsigned short* __restrict__ MKTB, float2* __restrict__ TR,
    unsigned short* __restrict__ XNb){
  int bid = blockIdx.x, tid = threadIdx.x;
  if (bid < 35520){
    int i = bid*256 + tid;  // float4 index
    const float* s; unsigned short* d; int off;
    if (i < 3571712){
      d = WCAT + (size_t)i*4;
      if      (i < 1048576){ s = av; off = i; }
      else if (i < 2097152){ s = ar; off = i-1048576; }
      else if (i < 3145728){ s = mr; off = i-2097152; }
      else if (i < 3276800){ s = aq; off = i-3145728; }
      else if (i < 3407872){ s = mv; off = i-3276800; }
      else if (i < 3538944){ s = mq; off = i-3407872; }
      else                 { s = mf; off = i-3538944; }
    }
    else if (i < 4620288){ off = i-3571712; s = ao; d = AOB  + (size_t)off*4; }
    else if (i < 4751360){ off = i-4620288; s = mo; d = MOB  + (size_t)off*4; }
    else if (i < 6193152){ off = i-4751360; s = f1;
      int row = off >> 9, c4 = off & 511;
      d = FFW + ((size_t)row*2)*2048 + c4*4; }
    else if (i < 7634944){ off = i-6193152; s = f2;
      int row = off >> 9, c4 = off & 511;
      d = FFW + ((size_t)row*2 + 1)*2048 + c4*4; }
    else if (i < 9076736){ off = i-7634944; s = fo; d = FFOB + (size_t)off*4; }
    else if (i < 9093120){ off = i-9076736; s = ak; d = AKB  + (size_t)off*4; }
    else return;
    float4 v = ((const float4*)s)[off];
    ushort4 o;
    o.x = f2b(v.x); o.y = f2b(v.y); o.z = f2b(v.z); o.w = f2b(v.w);
    *(ushort4*)d = o;
  } else if (bid < 35776){
    int i = bid - 35520, j = tid;
    MKTB[(size_t)j*256 + i] = f2b(mk[(size_t)i*256 + j]);
  } else if (bid < 35840){
    int idx = (bid - 35776)*256 + tid;   // 16384
    int pos = idx >> 7, j = idx & 127;
    float inv = powf(10000.f, -(float)j/128.f);
    float a = (float)pos * inv;
    TR[idx] = make_float2(cosf(a), sinf(a));
  } else {
    int row = bid - 35840;
    const float* xr = xsrc + (size_t)row*2048;
    float ss = 0.f;
    for (int j = tid; j < 2048; j += 256){ float v = xr[j]; ss += v*v; }
    __shared__ float red[256];
    red[tid] = ss; __syncthreads();
    for (int s = 128; s > 0; s >>= 1){ if (tid < s) red[tid] += red[tid+s]; __syncthreads(); }
    float scale = g1[0] / (sqrtf(red[0]) + 1e-8f);
    unsigned short* orow = XNb + (size_t)row*2048;
    for (int j4 = tid; j4 < 512; j4 += 256){
      float4 v = *(const float4*)(xr + j4*4);
      ushort4 o;
      o.x = f2b(v.x*scale); o.y = f2b(v.y*scale); o.z = f2b(v.z*scale); o.w = f2b(v.w*scale);
      ((ushort4*)orow)[j4] = o;
    }
  }
}

// ---------------- scale norm -> bf16 (for XS2) ----------------------------------
__global__ __launch_bounds__(256) void k_scalenorm_b(const float* __restrict__ x,
    const float* __restrict__ g, unsigned short* __restrict__ ob){
  int row = blockIdx.x, tid = threadIdx.x;
  const float* xr = x + (size_t)row*2048;
  float ss = 0.f;
  for (int j = tid; j < 2048; j += 256){ float v = xr[j]; ss += v*v; }
  __shared__ float red[256];
  red[tid] = ss; __syncthreads();
  for (int s = 128; s > 0; s >>= 1){ if (tid < s) red[tid] += red[tid+s]; __syncthreads(); }
  float scale = g[0] / (sqrtf(red[0]) + 1e-8f);
  unsigned short* orow = ob + (size_t)row*2048;
  for (int j4 = tid; j4 < 512; j4 += 256){
    float4 v = *(const float4*)(xr + j4*4);
    ushort4 o;
    o.x = f2b(v.x*scale); o.y = f2b(v.y*scale); o.z = f2b(v.z*scale); o.w = f2b(v.w*scale);
    ((ushort4*)orow)[j4] = o;
  }
}

// ---------------- pipelined bf16 MFMA GEMM (128x128): C = A @ B^T ---------------
// 128x128 tile, BK=32, 4 waves (64x64 each), 3 LDS buffers, counted vmcnt.
__global__ __launch_bounds__(256) void k_gemm_p(
    const unsigned short* __restrict__ A, int lda,
    const unsigned short* __restrict__ B,
    float* __restrict__ C, unsigned short* __restrict__ Cb,
    int N, int K, int ldc, int epi,
    const float* __restrict__ add,
    const unsigned short* __restrict__ gate, int gate_ld,
    const unsigned short* A2, const unsigned short* B2, float* C2){
  __shared__ unsigned short LDSu[24576];     // 48 KB
  int tid = threadIdx.x;
  int w = tid >> 6, l = tid & 63;
  int bi = blockIdx.y, bj = blockIdx.x;
  const unsigned short* Ap = A; const unsigned short* Bp = B; float* Cp = C;
  if (blockIdx.z){ Ap = A2; Bp = B2; Cp = C2; }
  int m0 = bi*128, n0 = bj*128;
  int wr = w >> 1, wc = w & 1;

  f32x4 acc[4][4];
#pragma unroll
  for (int i=0;i<4;++i)
#pragma unroll
    for (int j=0;j<4;++j){ f32x4 z = {0.f,0.f,0.f,0.f}; acc[i][j] = z; }

  const int r0 = tid >> 2;
  const int gsrc8 = (((tid&3) ^ ((tid>>3)&3)) * 8);

  auto stage = [&](int bs, int kt){
    unsigned short* db = LDSu + bs*8192;
    const unsigned short* ap0 = Ap + (size_t)(m0 + r0)*lda      + kt*32 + gsrc8;
    const unsigned short* ap1 = Ap + (size_t)(m0 + 64 + r0)*lda + kt*32 + gsrc8;
    const unsigned short* bp0 = Bp + (size_t)(n0 + r0)*K        + kt*32 + gsrc8;
    const unsigned short* bp1 = Bp + (size_t)(n0 + 64 + r0)*K   + kt*32 + gsrc8;
    __builtin_amdgcn_global_load_lds((const AS1 void*)ap0, (AS3 void*)(db + tid*8),        16, 0, 0);
    __builtin_amdgcn_global_load_lds((const AS1 void*)ap1, (AS3 void*)(db + 2048 + tid*8), 16, 0, 0);
    __builtin_amdgcn_global_load_lds((const AS1 void*)bp0, (AS3 void*)(db + 4096 + tid*8), 16, 0, 0);
    __builtin_amdgcn_global_load_lds((const AS1 void*)bp1, (AS3 void*)(db + 6144 + tid*8), 16, 0, 0);
  };

  const int nt = K >> 5;
  stage(0, 0);
  stage(1, 1);
  asm volatile("s_waitcnt vmcnt(4)" ::: "memory");
  __builtin_amdgcn_s_barrier();

  const int lr = l & 15;
  const int gsw = (((l>>4) ^ ((l>>1)&3)) * 8);
  const int aoff = (wr*64 + lr)*32 + gsw;
  const int boff = 4096 + (wc*64 + lr)*32 + gsw;

  int cur = 0;
  for (int t = 0; t < nt; ++t){
    if (t + 2 < nt) stage((t+2)%3, t+2);
    const unsigned short* Tb = LDSu + cur*8192;
    bhalf8 af[4], bfr[4];
#pragma unroll
    for (int m=0;m<4;++m) af[m]  = *(const bhalf8*)(Tb + aoff + m*512);
#pragma unroll
    for (int n=0;n<4;++n) bfr[n] = *(const bhalf8*)(Tb + boff + n*512);
    __builtin_amdgcn_s_setprio(1);
#pragma unroll
    for (int m=0;m<4;++m)
#pragma unroll
      for (int n=0;n<4;++n)
        acc[m][n] = __builtin_amdgcn_mfma_f32_16x16x32_bf16(af[m], bfr[n], acc[m][n], 0, 0, 0);
    __builtin_amdgcn_s_setprio(0);
    if (t + 1 < nt){
      if (t + 2 < nt){ asm volatile("s_waitcnt vmcnt(4)" ::: "memory"); }
      else           { asm volatile("s_waitcnt vmcnt(0)" ::: "memory"); }
      __builtin_amdgcn_s_barrier();
      cur = (cur == 2) ? 0 : cur + 1;
    }
  }

#pragma unroll
  for (int m=0;m<4;++m){
    int rowb = m0 + wr*64 + m*16 + ((l>>4)<<2);
#pragma unroll
    for (int r=0;r<4;++r){
      int row = rowb + r;
      size_t rbase = (size_t)row*ldc;
      size_t gbase = (size_t)row*gate_ld;
#pragma unroll
      for (int n=0;n<4;++n){
        int col = n0 + wc*64 + n*16 + (l&15);
        float v = acc[m][n][r];
        if (add) v += add[rbase + col];
        if (epi == 2) v *= sigmoidf_(b2f(gate[gbase + col]));
        if (epi == 3) Cb[rbase + col] = f2b(v);
        else          Cp[rbase + col] = v;
      }
    }
  }
}

// ---------------- combo1: small GEMMs (K=256) || scan1 --------------------------
// bid<64: z=bid>>5, bi=(bid>>1)&15, bj=bid&1 -> K0/QH GEMM.  bid>=64: scan1.
__global__ __launch_bounds__(256) void k_combo1(
    const unsigned short* __restrict__ CCb_, const unsigned short* __restrict__ AKB,
    const unsigned short* __restrict__ MKTB, float* __restrict__ K0f, float* __restrict__ QHf,
    const float* __restrict__ beta_p, const float* __restrict__ decay_p,
    float* __restrict__ CP, float* __restrict__ CQ){
  int bid = blockIdx.x, tid = threadIdx.x;
  if (bid < 64){
    __shared__ unsigned short LDSu[24576];
    int w = tid >> 6, l = tid & 63;
    int zz = bid >> 5, bi = (bid >> 1) & 15, bj = bid & 1;
    const unsigned short* Ap = zz ? (CCb_ + COL_QM) : (CCb_ + COL_QB);
    const unsigned short* Bp = zz ? MKTB : AKB;
    float* Cp = zz ? QHf : K0f;
    const int lda = CC_LD, K = 256, ldc = 256;
    int m0 = bi*128, n0 = bj*128;
    int wr = w >> 1, wc = w & 1;

    f32x4 acc[4][4];
#pragma unroll
    for (int i=0;i<4;++i)
#pragma unroll
      for (int j=0;j<4;++j){ f32x4 z = {0.f,0.f,0.f,0.f}; acc[i][j] = z; }

    const int r0 = tid >> 2;
    const int gsrc8 = (((tid&3) ^ ((tid>>3)&3)) * 8);

    auto stage = [&](int bs, int kt){
      unsigned short* db = LDSu + bs*8192;
      const unsigned short* ap0 = Ap + (size_t)(m0 + r0)*lda      + kt*32 + gsrc8;
      const unsigned short* ap1 = Ap + (size_t)(m0 + 64 + r0)*lda + kt*32 + gsrc8;
      const unsigned short* bp0 = Bp + (size_t)(n0 + r0)*K        + kt*32 + gsrc8;
      const unsigned short* bp1 = Bp + (size_t)(n0 + 64 + r0)*K   + kt*32 + gsrc8;
      __builtin_amdgcn_global_load_lds((const AS1 void*)ap0, (AS3 void*)(db + tid*8),        16, 0, 0);
      __builtin_amdgcn_global_load_lds((const AS1 void*)ap1, (AS3 void*)(db + 2048 + tid*8), 16, 0, 0);
      __builtin_amdgcn_global_load_lds((const AS1 void*)bp0, (AS3 void*)(db + 4096 + tid*8), 16, 0, 0);
      __builtin_amdgcn_global_load_lds((const AS1 void*)bp1, (AS3 void*)(db + 6144 + tid*8), 16, 0, 0);
    };

    const int nt = 8;
    stage(0, 0);
    stage(1, 1);
    asm volatile("s_waitcnt vmcnt(4)" ::: "memory");
    __builtin_amdgcn_s_barrier();

    const int lr = l & 15;
    const int gsw = (((l>>4) ^ ((l>>1)&3)) * 8);
    const int aoff = (wr*64 + lr)*32 + gsw;
    const int boff = 4096 + (wc*64 + lr)*32 + gsw;

    int cur = 0;
    for (int t = 0; t < nt; ++t){
      if (t + 2 < nt) stage((t+2)%3, t+2);
      const unsigned short* Tb = LDSu + cur*8192;
      bhalf8 af[4], bfr[4];
#pragma unroll
      for (int m=0;m<4;++m) af[m]  = *(const bhalf8*)(Tb + aoff + m*512);
#pragma unroll
      for (int n=0;n<4;++n) bfr[n] = *(const bhalf8*)(Tb + boff + n*512);
      __builtin_amdgcn_s_setprio(1);
#pragma unroll
      for (int m=0;m<4;++m)
#pragma unroll
        for (int n=0;n<4;++n)
          acc[m][n] = __builtin_amdgcn_mfma_f32_16x16x32_bf16(af[m], bfr[n], acc[m][n], 0, 0, 0);
      __builtin_amdgcn_s_setprio(0);
      if (t + 1 < nt){
        if (t + 2 < nt){ asm volatile("s_waitcnt vmcnt(4)" ::: "memory"); }
        else           { asm volatile("s_waitcnt vmcnt(0)" ::: "memory"); }
        __builtin_amdgcn_s_barrier();
        cur = (cur == 2) ? 0 : cur + 1;
      }
    }

#pragma unroll
    for (int m=0;m<4;++m){
      int rowb = m0 + wr*64 + m*16 + ((l>>4)<<2);
#pragma unroll
      for (int r=0;r<4;++r){
        size_t rbase = (size_t)(rowb + r)*ldc;
#pragma unroll
        for (int n=0;n<4;++n){
          int col = n0 + wc*64 + n*16 + (l&15);
          Cp[rbase + col] = acc[m][n][r];
        }
      }
    }
  } else {
    // ---- scan1: c = (bid-64)>>3, mg = (bid-64)&7 ----
    int idx = bid - 64;
    int c = idx >> 3, mg = idx & 7, d = tid;
    __shared__ float Fs[128];
    if (tid < 128){
      int s = tid >> 3, j = tid & 7;
      Fs[tid] = sigmoidf_(b2f(CCb_[(size_t)(c*16+s)*CC_LD + COL_FG + mg*8 + j]));
    }
    __syncthreads();
    float beta[8], gamma[8], Pa[8], Qa[8];
#pragma unroll
    for (int j=0;j<8;++j){
      int m = mg*8+j;
      beta[j]  = sigmoidf_(beta_p[m*256+d]);
      gamma[j] = (d < 192) ? 1.f : sigmoidf_(decay_p[m*64 + (d-192)]);
      Pa[j] = 1.f; Qa[j] = 0.f;
    }
    for (int s = 0; s < 16; ++s){
      float vm = b2f(CCb_[(size_t)(c*16+s)*CC_LD + COL_VM + d]);
#pragma unroll
      for (int j=0;j<8;++j){
        float f = Fs[s*8+j];
        float w = (1.f - f*beta[j])*gamma[j];
        Pa[j] *= w;
        Qa[j] = w*Qa[j] + f*vm;
      }
    }
#pragma unroll
    for (int j=0;j<8;++j){
      size_t oidx = ((size_t)c*64 + mg*8 + j)*256 + d;
      CP[oidx] = Pa[j]; CQ[oidx] = Qa[j];
    }
  }
}

// ---------------- combo2: attn scores+softmax (bid<32) || scan2 (bid>=32) -------
__global__ __launch_bounds__(256) void k_combo2(
    const unsigned short* __restrict__ CCqb, const float* __restrict__ K0,
    const float2* __restrict__ TR, unsigned short* __restrict__ P,
    const float* __restrict__ CP, const float* __restrict__ CQ, float* __restrict__ SIN){
  int bid = blockIdx.x, tid = threadIdx.x;
  if (bid < 32){
    __shared__ unsigned short Ks[128*256];   // 64 KB
    int c = bid;
    for (int it = 0; it < 16; ++it){
      int id = tid + it*256;
      int m = id >> 5;
      int cs = (id & 31) * 8;
      float v[8];
      if (c == 0 && m < 64){
#pragma unroll
        for (int u=0;u<8;++u) v[u] = 0.f;
      } else {
        int gr = (c-1)*64 + m;
        const float* kr = K0 + (size_t)gr*256 + cs;
        float4 x0 = *(const float4*)kr, x1 = *(const float4*)(kr+4);
        v[0]=x0.x; v[1]=x0.y; v[2]=x0.z; v[3]=x0.w;
        v[4]=x1.x; v[5]=x1.y; v[6]=x1.z; v[7]=x1.w;
#pragma unroll
        for (int p2=0;p2<4;++p2){
          float2 t = TR[m*128 + (cs>>1) + p2];
          float e = v[2*p2], o = v[2*p2+1];
          v[2*p2]   = e*t.x - o*t.y;
          v[2*p2+1] = o*t.x + e*t.y;
        }
      }
      unsigned short pk[8];
#pragma unroll
      for (int u=0;u<8;++u) pk[u] = f2b(v[u]);
      int byte = m*512 + ((cs*2) ^ ((m&7)<<4));
      *(bhalf8*)((char*)&Ks[0] + byte) = *(const bhalf8*)pk;
    }
    __syncthreads();

    int w = tid >> 6, l = tid & 63;
    int lr = l & 15, lkg = l >> 4;
    f32x4 acc[8];
#pragma unroll
    for (int n=0;n<8;++n){ f32x4 z = {0.f,0.f,0.f,0.f}; acc[n] = z; }

    int iq = w*16 + lr;
    const unsigned short* qbase = CCqb + (size_t)(c*64 + iq)*CC_LD;
    int pos = 64 + iq;

    for (int kt = 0; kt < 8; ++kt){
      int k0c = kt*32 + lkg*8;
      bhalf8 q8 = *(const bhalf8*)(qbase + k0c);
      float v[8];
#pragma unroll
      for (int u=0;u<8;++u) v[u] = b2f((unsigned short)(((short*)&q8)[u]));
#pragma unroll
      for (int p2=0;p2<4;++p2){
        float2 t = TR[pos*128 + (k0c>>1) + p2];
        float e = v[2*p2], o = v[2*p2+1];
        v[2*p2]   = e*t.x - o*t.y;
        v[2*p2+1] = o*t.x + e*t.y;
      }
      unsigned short pk[8];
#pragma unroll
      for (int u=0;u<8;++u) pk[u] = f2b(v[u]);
      bhalf8 af = *(const bhalf8*)pk;
#pragma unroll
      for (int n=0;n<8;++n){
        int m = n*16 + lr;
        int byte = m*512 + ((k0c*2) ^ ((m&7)<<4));
        bhalf8 bf = *(const bhalf8*)((const char*)&Ks[0] + byte);
        acc[n] = __builtin_amdgcn_mfma_f32_16x16x32_bf16(af, bf, acc[n], 0, 0, 0);
      }
    }

    int i0 = w*16 + lkg*4;
    float mx[4] = {-1e30f,-1e30f,-1e30f,-1e30f};
    float sm[4] = {0.f,0.f,0.f,0.f};
#pragma unroll
    for (int n=0;n<8;++n){
      int col = n*16 + lr;
#pragma unroll
      for (int r=0;r<4;++r){
        float vv = acc[n][r] * (1.f/16.f);
        if (col > i0 + r + 64) vv = -1e30f;
        acc[n][r] = vv;
        mx[r] = fmaxf(mx[r], vv);
      }
    }
#pragma unroll
    for (int s=1; s<16; s<<=1)
#pragma unroll
      for (int r=0;r<4;++r) mx[r] = fmaxf(mx[r], __shfl_xor(mx[r], s));
#pragma unroll
    for (int n=0;n<8;++n)
#pragma unroll
      for (int r=0;r<4;++r){
        float e = expf(acc[n][r] - mx[r]);
        acc[n][r] = e; sm[r] += e;
      }
#pragma unroll
    for (int s=1; s<16; s<<=1)
#pragma unroll
      for (int r=0;r<4;++r) sm[r] += __shfl_xor(sm[r], s);
    float rcp[4];
#pragma unroll
    for (int r=0;r<4;++r) rcp[r] = 1.f/sm[r];

    unsigned short* Pr = P + (size_t)c*8192;
#pragma unroll
    for (int n=0;n<8;++n){
      int col = n*16 + lr;
#pragma unroll
      for (int r=0;r<4;++r)
        Pr[(i0+r)*128 + col] = f2b(acc[n][r]*rcp[r]);
    }
  } else {
    // ---- scan2: m = bid-32 ----
    int m = bid - 32, d = tid;
    float S = 0.f;
    for (int c = 0; c < 128; ++c){
      size_t idx = ((size_t)c*64 + m)*256 + d;
      SIN[idx] = S;
      S = CP[idx]*S + CQ[idx];
    }
  }
}

// ---------------- combo3: MFMA PV (bid<512) || scan3 (bid>=512) -----------------
__global__ __launch_bounds__(256) void k_combo3(
    const unsigned short* __restrict__ P, const unsigned short* __restrict__ Vb, int vld,
    unsigned short* __restrict__ Y,
    const unsigned short* __restrict__ CC, const float* __restrict__ beta_p,
    const float* __restrict__ decay_p, const float* __restrict__ SIN,
    unsigned short* __restrict__ MEMS){
  int bid = blockIdx.x, tid = threadIdx.x;
  if (bid < 512){
    __shared__ unsigned short Vt[128*128];   // 32 KB
    int ct = bid & 15, c = bid >> 4;
    {
      int k = tid >> 1;
      int ch = (tid & 1) * 64;
      if (c == 0 && k < 64){
        for (int u=0; u<64; ++u){
          int col = ch + u;
          int byte = col*256 + ((k*2) ^ ((col&7)<<4));
          *(unsigned short*)((char*)&Vt[0] + byte) = 0;
        }
      } else {
        int gr = (c-1)*64 + k;
        const unsigned short* vr = Vb + (size_t)gr*vld + ct*128 + ch;
        for (int u8=0; u8<8; ++u8){
          bhalf8 x = *(const bhalf8*)(vr + u8*8);
#pragma unroll
          for (int u=0;u<8;++u){
            int col = ch + u8*8 + u;
            int byte = col*256 + ((k*2) ^ ((col&7)<<4));
            *(unsigned short*)((char*)&Vt[0] + byte) = (unsigned short)(((short*)&x)[u]);
          }
        }
      }
    }
    __syncthreads();
    int w = tid >> 6, l = tid & 63, lr = l & 15, lkg = l >> 4;
    f32x4 acc[8];
#pragma unroll
    for (int n=0;n<8;++n){ f32x4 z = {0.f,0.f,0.f,0.f}; acc[n] = z; }
    const unsigned short* Pr = P + (size_t)c*8192;
    for (int kt=0; kt<4; ++kt){
      int kb = kt*32 + lkg*8;
      bhalf8 af = *(const bhalf8*)(Pr + (w*16 + lr)*128 + kb);
#pragma unroll
      for (int n=0;n<8;++n){
        int col = n*16 + lr;
        int byte = col*256 + ((kb*2) ^ ((col&7)<<4));
        bhalf8 bf = *(const bhalf8*)((const char*)&Vt[0] + byte);
        acc[n] = __builtin_amdgcn_mfma_f32_16x16x32_bf16(af, bf, acc[n], 0, 0, 0);
      }
    }
    int row0 = c*64 + w*16 + lkg*4;
#pragma unroll
    for (int n=0;n<8;++n){
      int col = ct*128 + n*16 + lr;
#pragma unroll
      for (int r=0;r<4;++r)
        Y[(size_t)(row0+r)*2048 + col] = f2b(acc[n][r]);
    }
  } else {
    // ---- scan3: idx = bid-512, c = idx>>3, mg = idx&7 ----
    int idx = bid - 512;
    int c = idx >> 3, mg = idx & 7, d = tid;
    __shared__ float Fs[128];
    if (tid < 128){
      int s = tid >> 3, j = tid & 7;
      Fs[tid] = sigmoidf_(b2f(CC[(size_t)(c*16+s)*CC_LD + COL_FG + mg*8 + j]));
    }
    __syncthreads();
    float beta[8], gamma[8], S[8];
#pragma unroll
    for (int j=0;j<8;++j){
      int m = mg*8+j;
      beta[j]  = sigmoidf_(beta_p[m*256+d]);
      gamma[j] = (d < 192) ? 1.f : sigmoidf_(decay_p[m*64 + (d-192)]);
      S[j] = SIN[((size_t)c*64 + m)*256 + d];
    }
    for (int s = 0; s < 16; ++s){
      float vm = b2f(CC[(size_t)(c*16+s)*CC_LD + COL_VM + d]);
      size_t tb = (size_t)(c*16+s)*64;
#pragma unroll
      for (int j=0;j<8;++j){
        float f = Fs[s*8+j];
        float w = (1.f - f*beta[j])*gamma[j];
        S[j] = w*S[j] + f*vm;
        MEMS[(tb + mg*8 + j)*256 + d] = f2b(S[j]);
      }
    }
  }
}

// ---------------- BN=64 pipelined GEMM: C = A @ B^T + add (f32 out) -------------
__global__ __launch_bounds__(256) void k_gemm_p64(
    const unsigned short* __restrict__ A, int lda,
    const unsigned short* __restrict__ B,
    float* __restrict__ C, int K, int ldc,
    const float* __restrict__ add){
  __shared__ unsigned short LDSu[18432];     // 36 KB
  int tid = threadIdx.x;
  int w = tid >> 6, l = tid & 63;
  int bi = blockIdx.y, bj = blockIdx.x;
  int m0 = bi*128, n0 = bj*64;
  int wr = w >> 1, wc = w & 1;

  f32x4 acc[4][2];
#pragma unroll
  for (int i=0;i<4;++i)
#pragma unroll
    for (int j=0;j<2;++j){ f32x4 z = {0.f,0.f,0.f,0.f}; acc[i][j] = z; }

  const int r0 = tid >> 2;
  const int gsrc8 = (((tid&3) ^ ((tid>>3)&3)) * 8);

  auto stage = [&](int bs, int kt){
    unsigned short* db = LDSu + bs*6144;
    const unsigned short* ap0 = A + (size_t)(m0 + r0)*lda      + kt*32 + gsrc8;
    const unsigned short* ap1 = A + (size_t)(m0 + 64 + r0)*lda + kt*32 + gsrc8;
    const unsigned short* bp0 = B + (size_t)(n0 + r0)*K        + kt*32 + gsrc8;
    __builtin_amdgcn_global_load_lds((const AS1 void*)ap0, (AS3 void*)(db + tid*8),        16, 0, 0);
    __builtin_amdgcn_global_load_lds((const AS1 void*)ap1, (AS3 void*)(db + 2048 + tid*8), 16, 0, 0);
    __builtin_amdgcn_global_load_lds((const AS1 void*)bp0, (AS3 void*)(db + 4096 + tid*8), 16, 0, 0);
  };

  const int nt = K >> 5;
  stage(0, 0);
  stage(1, 1);
  asm volatile("s_waitcnt vmcnt(3)" ::: "memory");
  __builtin_amdgcn_s_barrier();

  const int lr = l & 15;
  const int gsw = (((l>>4) ^ ((l>>1)&3)) * 8);
  const int aoff = (wr*64 + lr)*32 + gsw;
  const int boff = 4096 + (wc*32 + lr)*32 + gsw;

  int cur = 0;
  for (int t = 0; t < nt; ++t){
    if (t + 2 < nt) stage((t+2)%3, t+2);
    const unsigned short* Tb = LDSu + cur*6144;
    bhalf8 af[4], bfr[2];
#pragma unroll
    for (int m=0;m<4;++m) af[m]  = *(const bhalf8*)(Tb + aoff + m*512);
#pragma unroll
    for (int n=0;n<2;++n) bfr[n] = *(const bhalf8*)(Tb + boff + n*512);
    __builtin_amdgcn_s_setprio(1);
#pragma unroll
    for (int m=0;m<4;++m)
#pragma unroll
      for (int n=0;n<2;++n)
        acc[m][n] = __builtin_amdgcn_mfma_f32_16x16x32_bf16(af[m], bfr[n], acc[m][n], 0, 0, 0);
    __builtin_amdgcn_s_setprio(0);
    if (t + 1 < nt){
      if (t + 2 < nt){ asm volatile("s_waitcnt vmcnt(3)" ::: "memory"); }
      else           { asm volatile("s_waitcnt vmcnt(0)" ::: "memory"); }
      __builtin_amdgcn_s_barrier();
      cur = (cur == 2) ? 0 : cur + 1;
    }
  }

#pragma unroll
  for (int m=0;m<4;++m){
    int rowb = m0 + wr*64 + m*16 + ((l>>4)<<2);
#pragma unroll
    for (int r=0;r<4;++r){
      int row = rowb + r;
      size_t rbase = (size_t)row*ldc;
#pragma unroll
      for (int n=0;n<2;++n){
        int col = n0 + wc*32 + n*16 + (l&15);
        C[rbase + col] = acc[m][n][r] + add[rbase + col];
      }
    }
  }
}

// ---------------- BN=64 fused AO+MO GEMM -> XS2 ---------------------------------
__global__ __launch_bounds__(256) void k_gemm_fuse2_64(
    const unsigned short* __restrict__ A,  const unsigned short* __restrict__ B,
    const unsigned short* __restrict__ A2, const unsigned short* __restrict__ B2,
    const unsigned short* __restrict__ gate1, const unsigned short* __restrict__ gate2,
    const float* __restrict__ xs, float* __restrict__ XS2){
  __shared__ unsigned short LDSu[18432];
  int tid = threadIdx.x;
  int w = tid >> 6, l = tid & 63;
  int bi = blockIdx.y, bj = blockIdx.x;
  int m0 = bi*128, n0 = bj*64;
  int wr = w >> 1, wc = w & 1;

  f32x4 acc[4][2], acc2[4][2];
#pragma unroll
  for (int i=0;i<4;++i)
#pragma unroll
    for (int j=0;j<2;++j){ f32x4 z = {0.f,0.f,0.f,0.f}; acc[i][j] = z; acc2[i][j] = z; }

  const int r0 = tid >> 2;
  const int gsrc8 = (((tid&3) ^ ((tid>>3)&3)) * 8);

  auto stage = [&](int bs, int kt, const unsigned short* Ap, int lda,
                   const unsigned short* Bp, int ldb){
    unsigned short* db = LDSu + bs*6144;
    const unsigned short* ap0 = Ap + (size_t)(m0 + r0)*lda      + kt*32 + gsrc8;
    const unsigned short* ap1 = Ap + (size_t)(m0 + 64 + r0)*lda + kt*32 + gsrc8;
    const unsigned short* bp0 = Bp + (size_t)(n0 + r0)*ldb      + kt*32 + gsrc8;
    __builtin_amdgcn_global_load_lds((const AS1 void*)ap0, (AS3 void*)(db + tid*8),        16, 0, 0);
    __builtin_amdgcn_global_load_lds((const AS1 void*)ap1, (AS3 void*)(db + 2048 + tid*8), 16, 0, 0);
    __builtin_amdgcn_global_load_lds((const AS1 void*)bp0, (AS3 void*)(db + 4096 + tid*8), 16, 0, 0);
  };

  const int lr = l & 15;
  const int gsw = (((l>>4) ^ ((l>>1)&3)) * 8);
  const int aoff = (wr*64 + lr)*32 + gsw;
  const int boff = 4096 + (wc*32 + lr)*32 + gsw;

  {
    const int nt = 64;
    stage(0, 0, A, 2048, B, 2048);
    stage(1, 1, A, 2048, B, 2048);
    asm volatile("s_waitcnt vmcnt(3)" ::: "memory");
    __builtin_amdgcn_s_barrier();
    int cur = 0;
    for (int t = 0; t < nt; ++t){
      if (t + 2 < nt) stage((t+2)%3, t+2, A, 2048, B, 2048);
      const unsigned short* Tb = LDSu + cur*6144;
      bhalf8 af[4], bfr[2];
#pragma unroll
      for (int m=0;m<4;++m) af[m]  = *(const bhalf8*)(Tb + aoff + m*512);
#pragma unroll
      for (int n=0;n<2;++n) bfr[n] = *(const bhalf8*)(Tb + boff + n*512);
      __builtin_amdgcn_s_setprio(1);
#pragma unroll
      for (int m=0;m<4;++m)
#pragma unroll
        for (int n=0;n<2;++n)
          acc[m][n] = __builtin_amdgcn_mfma_f32_16x16x32_bf16(af[m], bfr[n], acc[m][n], 0, 0, 0);
      __builtin_amdgcn_s_setprio(0);
      if (t + 1 < nt){
        if (t + 2 < nt){ asm volatile("s_waitcnt vmcnt(3)" ::: "memory"); }
        else           { asm volatile("s_waitcnt vmcnt(0)" ::: "memory"); }
        __builtin_amdgcn_s_barrier();
        cur = (cur == 2) ? 0 : cur + 1;
      }
    }
  }
  __syncthreads();

  {
    const int nt = 8;
    stage(0, 0, A2, 256, B2, 256);
    stage(1, 1, A2, 256, B2, 256);
    asm volatile("s_waitcnt vmcnt(3)" ::: "memory");
    __builtin_amdgcn_s_barrier();
    int cur = 0;
    for (int t = 0; t < nt; ++t){
      if (t + 2 < nt) stage((t+2)%3, t+2, A2, 256, B2, 256);
      const unsigned short* Tb = LDSu + cur*6144;
      bhalf8 af[4], bfr[2];
#pragma unroll
      for (int m=0;m<4;++m) af[m]  = *(const bhalf8*)(Tb + aoff + m*512);
#pragma unroll
      for (int n=0;n<2;++n) bfr[n] = *(const bhalf8*)(Tb + boff + n*512);
      __builtin_amdgcn_s_setprio(1);
#pragma unroll
      for (int m=0;m<4;++m)
#pragma unroll
        for (int n=0;n<2;++n)
          acc2[m][n] = __builtin_amdgcn_mfma_f32_16x16x32_bf16(af[m], bfr[n], acc2[m][n], 0, 0, 0);
      __builtin_amdgcn_s_setprio(0);
      if (t + 1 < nt){
        if (t + 2 < nt){ asm volatile("s_waitcnt vmcnt(3)" ::: "memory"); }
        else           { asm volatile("s_waitcnt vmcnt(0)" ::: "memory"); }
        __builtin_amdgcn_s_barrier();
        cur = (cur == 2) ? 0 : cur + 1;
      }
    }
  }

#pragma unroll
  for (int m=0;m<4;++m){
    int rowb = m0 + wr*64 + m*16 + ((l>>4)<<2);
#pragma unroll
    for (int r=0;r<4;++r){
      int row = rowb + r;
      size_t gb = (size_t)row*CC_LD;
      size_t rb = (size_t)row*2048;
#pragma unroll
      for (int n=0;n<2;++n){
        int col = n0 + wc*32 + n*16 + (l&15);
        float v = acc[m][n][r]*sigmoidf_(b2f(gate1[gb + col]))
                + acc2[m][n][r]*sigmoidf_(b2f(gate2[gb + col]))
                + xs[rb + col];
        XS2[rb + col] = v;
      }
    }
  }
}

// ---------------- SiLU-pair GEMM (FF-in) ----------------------------------------
__global__ __launch_bounds__(256) void k_gemm_silu(
    const unsigned short* __restrict__ A, int lda,
    const unsigned short* __restrict__ B,
    unsigned short* __restrict__ Cb, int K, int out_ld){
  __shared__ unsigned short LDSu[24576];
  int tid = threadIdx.x;
  int w = tid >> 6, l = tid & 63;
  int bi = blockIdx.y, bj = blockIdx.x;
  int m0 = bi*128, n0 = bj*128;
  int wr = w >> 1, wc = w & 1;

  f32x4 acc[4][4];
#pragma unroll
  for (int i=0;i<4;++i)
#pragma unroll
    for (int j=0;j<4;++j){ f32x4 z = {0.f,0.f,0.f,0.f}; acc[i][j] = z; }

  const int r0 = tid >> 2;
  const int gsrc8 = (((tid&3) ^ ((tid>>3)&3)) * 8);

  auto stage = [&](int bs, int kt){
    unsigned short* db = LDSu + bs*8192;
    const unsigned short* ap0 = A + (size_t)(m0 + r0)*lda      + kt*32 + gsrc8;
    const unsigned short* ap1 = A + (size_t)(m0 + 64 + r0)*lda + kt*32 + gsrc8;
    const unsigned short* bp0 = B + (size_t)(n0 + r0)*K        + kt*32 + gsrc8;
    const unsigned short* bp1 = B + (size_t)(n0 + 64 + r0)*K   + kt*32 + gsrc8;
    __builtin_amdgcn_global_load_lds((const AS1 void*)ap0, (AS3 void*)(db + tid*8),        16, 0, 0);
    __builtin_amdgcn_global_load_lds((const AS1 void*)ap1, (AS3 void*)(db + 2048 + tid*8), 16, 0, 0);
    __builtin_amdgcn_global_load_lds((const AS1 void*)bp0, (AS3 void*)(db + 4096 + tid*8), 16, 0, 0);
    __builtin_amdgcn_global_load_lds((const AS1 void*)bp1, (AS3 void*)(db + 6144 + tid*8), 16, 0, 0);
  };

  const int nt = K >> 5;
  stage(0, 0);
  stage(1, 1);
  asm volatile("s_waitcnt vmcnt(4)" ::: "memory");
  __builtin_amdgcn_s_barrier();

  const int lr = l & 15;
  const int gsw = (((l>>4) ^ ((l>>1)&3)) * 8);
  const int aoff = (wr*64 + lr)*32 + gsw;
  const int boff = 4096 + (wc*64 + lr)*32 + gsw;

  int cur = 0;
  for (int t = 0; t < nt; ++t){
    if (t + 2 < nt) stage((t+2)%3, t+2);
    const unsigned short* Tb = LDSu + cur*8192;
    bhalf8 af[4], bfr[4];
#pragma unroll
    for (int m=0;m<4;++m) af[m]  = *(const bhalf8*)(Tb + aoff + m*512);
#pragma unroll
    for (int n=0;n<4;++n) bfr[n] = *(const bhalf8*)(Tb + boff + n*512);
    __builtin_amdgcn_s_setprio(1);
#pragma unroll
    for (int m=0;m<4;++m)
#pragma unroll
      for (int n=0;n<4;++n)
        acc[m][n] = __builtin_amdgcn_mfma_f32_16x16x32_bf16(af[m], bfr[n], acc[m][n], 0, 0, 0);
    __builtin_amdgcn_s_setprio(0);
    if (t + 1 < nt){
      if (t + 2 < nt){ asm volatile("s_waitcnt vmcnt(4)" ::: "memory"); }
      else           { asm volatile("s_waitcnt vmcnt(0)" ::: "memory"); }
      __builtin_amdgcn_s_barrier();
      cur = (cur == 2) ? 0 : cur + 1;
    }
  }

#pragma unroll
  for (int m=0;m<4;++m){
    int rowb = m0 + wr*64 + m*16 + ((l>>4)<<2);
#pragma unroll
    for (int r=0;r<4;++r){
      int row = rowb + r;
      size_t gbase = (size_t)row*out_ld;
#pragma unroll
      for (int n=0;n<4;++n){
        int col = n0 + wc*64 + n*16 + (l&15);
        float v = acc[m][n][r];
        float o = __shfl_xor(v, 1);
        if ((l & 1) == 0)
          Cb[gbase + (col>>1)] = f2b(v*sigmoidf_(v)*o);
      }
    }
  }
}

// ---------------- mem readout (wave-parallel softmax, vectorized pass 2) --------
__global__ __launch_bounds__(256) void k_memread(const unsigned short* __restrict__ MEMS,
    const float* __restrict__ QH, const unsigned short* __restrict__ QMs, int qm_ld,
    const float* __restrict__ L, unsigned short* __restrict__ YMb){
  int t = blockIdx.x, tid = threadIdx.x;
  int wave = tid >> 6, lane = tid & 63;
  __shared__ float anorm[64];
  __shared__ float red2[4][64][4];
  const unsigned short* Mt = MEMS + (size_t)t*16384;
  float4 qh4 = *(const float4*)(QH + (size_t)t*256 + lane*4);
  ushort4 qmu = *(const ushort4*)(QMs + (size_t)t*qm_ld + lane*4);
  float qm0 = b2f(qmu.x), qm1 = b2f(qmu.y), qm2 = b2f(qmu.z), qm3 = b2f(qmu.w);
  for (int mi = 0; mi < 16; ++mi){
    int m = wave*16 + mi;
    ushort4 su = *(const ushort4*)(Mt + m*256 + lane*4);
    float4 l4 = *(const float4*)(L + (size_t)m*256 + lane*4);
    float p = b2f(su.x)*qh4.x + b2f(su.y)*qh4.y + b2f(su.z)*qh4.z + b2f(su.w)*qh4.w
            + l4.x*qm0 + l4.y*qm1 + l4.z*qm2 + l4.w*qm3;
#pragma unroll
    for (int off = 32; off > 0; off >>= 1) p += __shfl_down(p, off);
    if (lane == 0) anorm[m] = p * (1.f/16.f);
  }
  __syncthreads();
  if (tid < 64){
    float v = anorm[tid];
    float mx = v;
#pragma unroll
    for (int off = 32; off > 0; off >>= 1) mx = fmaxf(mx, __shfl_xor(mx, off));
    float e = expf(v - mx);
    float s = e;
#pragma unroll
    for (int off = 32; off > 0; off >>= 1) s += __shfl_xor(s, off);
    anorm[tid] = e / s;
  }
  __syncthreads();
  int mq = tid >> 6, dq = tid & 63;
  float a0=0.f, a1=0.f, a2=0.f, a3=0.f;
#pragma unroll
  for (int mi = 0; mi < 16; ++mi){
    int m = mq*16 + mi;
    ushort4 su = *(const ushort4*)(Mt + m*256 + dq*4);
    float wgt = anorm[m];
    a0 += wgt*b2f(su.x); a1 += wgt*b2f(su.y);
    a2 += wgt*b2f(su.z); a3 += wgt*b2f(su.w);
  }
  red2[mq][dq][0]=a0; red2[mq][dq][1]=a1; red2[mq][dq][2]=a2; red2[mq][dq][3]=a3;
  __syncthreads();
  if (tid < 64){
    float r0=0.f, r1=0.f, r2=0.f, r3=0.f;
#pragma unroll
    for (int g=0; g<4; ++g){
      r0 += red2[g][tid][0]; r1 += red2[g][tid][1];
      r2 += red2[g][tid][2]; r3 += red2[g][tid][3];
    }
    ushort4 o;
    o.x = f2b(r0); o.y = f2b(r1); o.z = f2b(r2); o.w = f2b(r3);
    *(ushort4*)(YMb + (size_t)t*256 + tid*4) = o;
  }
}

// ---------------- launch ---------------------------------------------------------
extern "C" void kernel_launch(void* const* d_in, const int* in_sizes, int n_in,
                              void* d_out, int out_size, void* d_ws, size_t ws_size,
                              hipStream_t stream){
  const float* xs        = (const float*)d_in[0];
  const float* attn_q    = (const float*)d_in[1];
  const float* attn_k    = (const float*)d_in[2];
  const float* attn_v    = (const float*)d_in[3];
  const float* attn_o    = (const float*)d_in[4];
  const float* attn_r    = (const float*)d_in[5];
  const float* mem_f     = (const float*)d_in[6];
  const float* mem_q     = (const float*)d_in[7];
  const float* mem_k     = (const float*)d_in[8];
  const float* mem_v     = (const float*)d_in[9];
  const float* mem_o     = (const float*)d_in[10];
  const float* mem_r     = (const float*)d_in[11];
  const float* mem_beta  = (const float*)d_in[12];
  const float* mem_decay = (const float*)d_in[13];
  const float* mem_l     = (const float*)d_in[14];
  const float* ff1       = (const float*)d_in[15];
  const float* ff2       = (const float*)d_in[16];
  const float* ffo       = (const float*)d_in[17];
  const float* sn1       = (const float*)d_in[18];
  const float* sn2       = (const float*)d_in[19];
  float* out = (float*)d_out;
  float* W = (float*)d_ws;

  // ---- workspace layout (float offsets), ~246 MB ----
  unsigned short* XNb  = (unsigned short*)(W + 0);           // 2,097,152
  unsigned short* WCAT = (unsigned short*)(W + 2097152);     // 7,340,032 (7168x2048)
  unsigned short* CCb  = (unsigned short*)(W + 9437184);     // 7,340,032 (2048x7168)
  unsigned short* AOB  = (unsigned short*)(W + 16777216);    // 2,097,152
  unsigned short* MOB  = (unsigned short*)(W + 18874368);    // 262,144
  unsigned short* FFW  = (unsigned short*)(W + 19136512);    // 5,767,168 (interleaved ff1/ff2)
  unsigned short* FFOB = (unsigned short*)(W + 24903680);    // 2,883,584
  unsigned short* AKB  = (unsigned short*)(W + 27787264);    // 32,768
  unsigned short* MKTB = (unsigned short*)(W + 27820032);    // 32,768
  unsigned short* Ybb  = (unsigned short*)(W + 27852800);    // 2,097,152
  float*          XS2  = W + 34144256;                       // 4,194,304
  unsigned short* MEMSb= (unsigned short*)(W + 38338560);    // 16,777,216
  float*          CP   = W + 55115776;                       // 2,097,152 (128x64x256)
  float*          CQ   = W + 57212928;                       // 2,097,152
  float*          SIN  = W + 59310080;                       // 2,097,152
  float2*         TRIG = (float2*)(W + 61407232);            // 32,768 fl
  // aliases (sequential liveness):
  float*          K0   = W + 32768;                          // over XNb (dead after CC GEMM)
  unsigned short* P    = (unsigned short*)(W + 557056);      // over XNb
  float*          QH   = W + 688128;                         // over XNb
  unsigned short* YMb  = (unsigned short*)(W + 1212416);     // over XNb
  unsigned short* XN2b = MEMSb;                              // over MEMSb (dead after memread)
  unsigned short* H1b  = (unsigned short*)(W + 40435712);    // over MEMSb tail (2048x2816 bf16)

  dim3 blk(256);

  // ---- mega prep: converts + mem_k transpose + trig + scalenorm1 ----
  k_prep<<<dim3(37888), blk, 0, stream>>>(attn_v, attn_r, mem_r, attn_q, mem_v, mem_q,
      mem_f, attn_o, mem_o, ff1, ff2, ffo, attn_k, mem_k, xs, sn1,
      WCAT, AOB, MOB, FFW, FFOB, AKB, MKTB, TRIG, XNb);

  // ---- BIG concat GEMM (V + gates + QB + VM + QM + FG), bf16 out ----
  k_gemm_p<<<dim3(56, 16), blk, 0, stream>>>(XNb, 2048, WCAT, nullptr, CCb, CC_LD, 2048, CC_LD, 3,
      nullptr, nullptr, 0, nullptr, nullptr, nullptr);

  // ---- combo1: small GEMMs (K0, QH) || scan1 ----
  k_combo1<<<dim3(1088), blk, 0, stream>>>(CCb, AKB, MKTB, K0, QH,
      mem_beta, mem_decay, CP, CQ);

  // ---- combo2: attn scores+softmax || scan2 ----
  k_combo2<<<dim3(96), blk, 0, stream>>>(CCb + COL_QB, K0, TRIG, P, CP, CQ, SIN);

  // ---- combo3: PV || scan3 ----
  k_combo3<<<dim3(1536), blk, 0, stream>>>(P, CCb + COL_V, CC_LD, Ybb,
      CCb, mem_beta, mem_decay, SIN, MEMSb);

  // ---- mem readout ----
  k_memread<<<dim3(2048), blk, 0, stream>>>(MEMSb, QH, CCb + COL_QM, CC_LD, mem_l, YMb);

  // ---- fused AO+MO -> XS2 = attn_out + mem_out + xs (BN=64, 512 blocks) ----
  k_gemm_fuse2_64<<<dim3(32, 16), blk, 0, stream>>>(Ybb, AOB, YMb, MOB,
      CCb + COL_B1, CCb + COL_B2, xs, XS2);

  // ---- xn2 = scalenorm(XS2) -> bf16 ----
  k_scalenorm_b<<<dim3(2048), blk, 0, stream>>>(XS2, sn2, XN2b);

  // ---- FF: SiLU-fused GEMM -> H1b, then BN=64 out GEMM (512 blocks) ----
  k_gemm_silu<<<dim3(44, 16), blk, 0, stream>>>(XN2b, 2048, FFW, H1b, 2048, 2816);
  k_gemm_p64<<<dim3(32, 16), blk, 0, stream>>>(H1b, 2816, FFOB, out, 2816, 2048, XS2);
}